// Round 13
// baseline (1245.609 us; speedup 1.0000x reference)
//
#include <hip/hip_runtime.h>
#include <math.h>

static constexpr int B_   = 32;
static constexpr int L_   = 1024;
static constexpr int CIN_ = 21;
static constexpr int D_   = 512;
static constexpr int H_   = 8;
static constexpr int E_   = 64;
static constexpr int DFF_ = 2048;
static constexpr int M_   = 64;   // MODES

typedef unsigned short u16;
typedef __attribute__((ext_vector_type(8))) short bf16x8;
typedef __attribute__((ext_vector_type(4))) float f32x4;
typedef __attribute__((ext_vector_type(4))) unsigned short u16x4;

// RNE float->bf16 (bit-level, no header dependency)
static __device__ __forceinline__ u16 f2b(float f) {
    unsigned u = __float_as_uint(f);
    unsigned r = (u + 0x7fffu + ((u >> 16) & 1u)) >> 16;
    return (u16)r;
}
static __device__ __forceinline__ float b2f(u16 x) {
    return __uint_as_float((unsigned)x << 16);
}

// async global->LDS 16B/lane copy (CK-style int-roundtrip AS casts;
// LDS dest is wave-uniform, lanes land at base + lane*16)
static __device__ __forceinline__ void gload16(const u16* g, u16* l) {
    unsigned long long ga = (unsigned long long)g;
    unsigned la = (unsigned)(unsigned long long)l;   // low 32 bits = LDS offset
    __builtin_amdgcn_global_load_lds(
        (const __attribute__((address_space(1))) void*)ga,
        (__attribute__((address_space(3))) void*)(unsigned long long)la,
        16, 0, 0);
}

// ---------------------------------------------------------------------------
// Tables (fp32 trig): TRIG16 [128 mcat][1024 l] (rows 0-63 cos, 64-127 -sin);
// TCAT16 [1024][128] inverse-DFT coefficients (1/1024 baked in);
// PE fp32 [1024][512].
// ---------------------------------------------------------------------------
__global__ void k_tables(u16* trig, u16* tcat, float* pe) {
    int idx = blockIdx.x * 256 + threadIdx.x;   // 0 .. 524287
    if (idx < 131072) {                          // trig [mc][l]
        int l = idx & 1023, mc = idx >> 10;
        int m = mc & 63;
        float th = (float)((m * l) & 1023) * 0.006135923151542565f; // 2pi/1024
        float v = (mc < 64) ? cosf(th) : (-sinf(th));
        trig[idx] = f2b(v);
    }
    if (idx < 131072) {                          // tcat [l][k]
        int k = idx & 127, l = idx >> 7;
        int m = k & 63;
        float th = (float)((m * l) & 1023) * 0.006135923151542565f;
        float v;
        if (k < 64) v = (m == 0) ? 1.0f : (2.0f * cosf(th));
        else        v = (m == 0) ? 0.0f : (-2.0f * sinf(th));
        tcat[idx] = f2b(v * (1.0f / 1024.0f));
    }
    if (idx < 524288) {                          // pe [l][d]
        int d = idx & 511, l = idx >> 9;
        int i2 = d >> 1;
        float div = expf(-(float)(2 * i2) * 0.017988946039015984f);
        float arg = (float)l * div;
        pe[idx] = (d & 1) ? cosf(arg) : sinf(arg);
    }
}

// generic fp32 -> bf16 cast (n multiple of 4)
__global__ void k_cast(const float* __restrict__ in, u16* __restrict__ out, int n4) {
    int i = blockIdx.x * 256 + threadIdx.x;
    if (i < n4) {
        float4 v = ((const float4*)in)[i];
        u16x4 o = { f2b(v.x), f2b(v.y), f2b(v.z), f2b(v.w) };
        ((u16x4*)out)[i] = o;
    }
}

// ---------------------------------------------------------------------------
// Fourier-weight transpose: [h][e][o][m] fp32 -> [h][m][e*64+o] bf16.
// LDS-tiled, both sides coalesced. grid (64 eo-tiles, 8 h, 2 re/im).
// ---------------------------------------------------------------------------
__global__ void k_wtrans(const float* __restrict__ re, const float* __restrict__ im,
                         u16* __restrict__ outre, u16* __restrict__ outim) {
    __shared__ float t[64][65];
    const float* src = blockIdx.z ? im : re;
    u16* dst = blockIdx.z ? outim : outre;
    int h = blockIdx.y, eo0 = blockIdx.x * 64;
    int j = threadIdx.x & 63, i0 = threadIdx.x >> 6;
    for (int i = i0; i < 64; i += 4)
        t[i][j] = src[(size_t)h * 262144 + (size_t)(eo0 + i) * 64 + j];
    __syncthreads();
    for (int i = i0; i < 64; i += 4)
        dst[(size_t)h * 262144 + (size_t)i * 4096 + eo0 + j] = f2b(t[j][i]);
}

// ---------------------------------------------------------------------------
// Embedding: circular conv1d(k=3) + PE table. Block = 512 threads (one per d),
// 16 l-values per thread (2048 blocks -> latency-bound fix); x_enc strip in
// LDS; rolling 2-row register window.
// ---------------------------------------------------------------------------
__global__ __launch_bounds__(512) void k_embed(
        const float* __restrict__ xe, const float* __restrict__ cw,
        const float* __restrict__ pe, float* __restrict__ x32,
        u16* __restrict__ x16) {
    __shared__ float strip[18][21];
    int b = blockIdx.y, l0 = blockIdx.x * 16;
    int d = threadIdx.x;
    if (d < 18 * 21) {
        int r = d / 21, c = d - r * 21;
        int ls = (l0 + r - 1 + 1024) & 1023;
        strip[r][c] = xe[((size_t)b * 1024 + ls) * 21 + c];
    }
    __syncthreads();
    float w[3][21];
    #pragma unroll
    for (int k = 0; k < 3; ++k)
        #pragma unroll
        for (int c = 0; c < 21; ++c)
            w[k][c] = cw[(size_t)d * 63 + c * 3 + k];
    float a0[21], a1[21];
    #pragma unroll
    for (int c = 0; c < 21; ++c) { a0[c] = strip[0][c]; a1[c] = strip[1][c]; }
    for (int li = 0; li < 16; ++li) {
        float acc = 0.f;
        #pragma unroll
        for (int c = 0; c < 21; ++c) {
            float a2 = strip[li + 2][c];
            acc += w[0][c] * a0[c] + w[1][c] * a1[c] + w[2][c] * a2;
            a0[c] = a1[c]; a1[c] = a2;
        }
        int l = l0 + li;
        float v = acc + pe[(size_t)l * 512 + d];
        size_t o = ((size_t)b * 1024 + l) * 512 + d;
        x32[o] = v;
        x16[o] = f2b(v);
    }
}

// ---------------------------------------------------------------------------
// bf16 MFMA NT GEMM: 128x128 tile, 4 waves, 16x16x32 MFMA, BK=64 (half the
// barriers of BK=32 — 2-phase cost is stage+vmcnt+barrier), global_load_lds
// staging, 3 blocks/CU. BIAS per-col, BIASR per-row.
// DFTZ: transposed-output DFT mode — grid (4 c-tiles, 1, 128 z):
//   z = ks*32+b; A(=TRIG) += ks*256, W(=qT) += b*1024 + ks*256,
//   C partial at z*65536, layout [mc][c].
// ---------------------------------------------------------------------------
template<bool BIAS, bool BIASR, bool GELU, bool ADD, bool WF32, bool WBF16,
         bool DFTZ = false>
__global__ __launch_bounds__(256, 3) void k_mfma(
        const u16* __restrict__ A, const u16* __restrict__ W,
        const float* __restrict__ bias, const float* addp,
        float* C32, u16* C16,
        int K, int lda, int ldw, int ldc, long strideA, long strideC) {
    __shared__ __align__(16) u16 As[128 * 64];
    __shared__ __align__(16) u16 Bs[128 * 64];
    const int tid  = threadIdx.x;
    const int lane = tid & 63, wid = tid >> 6;
    int m0, n0;
    size_t cbase;
    if constexpr (DFTZ) {
        int z  = blockIdx.z;
        int ks = z >> 5;                     // K-slice 0..3
        m0 = 0;
        n0 = blockIdx.x * 128;
        A += (size_t)ks * 256;
        W += (size_t)(z & 31) * 1024 + (size_t)ks * 256;
        cbase = (size_t)z * 65536;
    } else {
        m0 = blockIdx.y * 128;
        n0 = blockIdx.x * 128;
        A += (size_t)blockIdx.z * strideA;
        cbase = (size_t)blockIdx.z * strideC;
    }

    // staging (BK=64, rows 128B): wave wid owns rows [32*wid, 32*wid+32);
    // each gload16 covers 8 rows: lane l -> row (l>>3), col elem 8*(l&7).
    const int srow = lane >> 3, scol = (lane & 7) * 8;
    const u16* gaP = A + (size_t)(m0 + wid * 32 + srow) * lda + scol;
    const u16* gbP = W + (size_t)(n0 + wid * 32 + srow) * ldw + scol;

    const int wr = wid >> 1, wc = wid & 1;
    const int fr = lane & 15, fg = lane >> 4;

    f32x4 acc[4][4];
    #pragma unroll
    for (int i = 0; i < 4; ++i)
        #pragma unroll
        for (int j = 0; j < 4; ++j)
            acc[i][j] = f32x4{0.f, 0.f, 0.f, 0.f};

    for (int k0 = 0; k0 < K; k0 += 64) {
        __syncthreads();                    // prev iter's ds_reads done
        #pragma unroll
        for (int i = 0; i < 4; ++i) {
            gload16(gaP + (size_t)(8 * i) * lda + k0, &As[(wid * 32 + 8 * i) * 64]);
            gload16(gbP + (size_t)(8 * i) * ldw + k0, &Bs[(wid * 32 + 8 * i) * 64]);
        }
        __syncthreads();                    // vmcnt(0) drained -> tile ready
        #pragma unroll
        for (int ks = 0; ks < 2; ++ks) {
            bf16x8 af[4], bfr[4];
            #pragma unroll
            for (int i = 0; i < 4; ++i) {
                af[i]  = *(const bf16x8*)&As[(wr * 64 + i * 16 + fr) * 64 + ks * 32 + fg * 8];
                bfr[i] = *(const bf16x8*)&Bs[(wc * 64 + i * 16 + fr) * 64 + ks * 32 + fg * 8];
            }
            #pragma unroll
            for (int i = 0; i < 4; ++i)
                #pragma unroll
                for (int j = 0; j < 4; ++j)
                    acc[i][j] = __builtin_amdgcn_mfma_f32_16x16x32_bf16(
                        af[i], bfr[j], acc[i][j], 0, 0, 0);
        }
    }

    #pragma unroll
    for (int i = 0; i < 4; ++i) {
        #pragma unroll
        for (int j = 0; j < 4; ++j) {
            #pragma unroll
            for (int r = 0; r < 4; ++r) {
                int row = m0 + wr * 64 + i * 16 + fg * 4 + r;
                int col = n0 + wc * 64 + j * 16 + fr;
                float v = acc[i][j][r];
                if (BIAS)  v += bias[col];
                if (BIASR) v += bias[row];
                if (GELU) v = 0.5f * v * (1.f + erff(v * 0.70710678118f));
                size_t o = cbase + (size_t)row * ldc + col;
                if (ADD)  v += addp[o];
                if (WF32) C32[o] = v;
                if (WBF16) C16[o] = f2b(v);
            }
        }
    }
}

// ---------------------------------------------------------------------------
// Complex per-mode channel mix. Inputs: ftt partials [z=ks*32+b][mc=128][c=512]
// (4 K-slices summed here, lane-contiguous in c) and transposed bf16 weights
// WT [h][m][e*64+o]. Output acat bf16 [B*H*64o][128] (Re | Im).
// grid 512 = (h,m), block 256.
// ---------------------------------------------------------------------------
__global__ void k_modemix(const float* __restrict__ ftT,
                          const u16* __restrict__ wtre, const u16* __restrict__ wtim,
                          u16* __restrict__ acat) {
    __shared__ float wr_s[64][64];   // [e][o]
    __shared__ float wi_s[64][64];
    __shared__ float fr_s[32][64];   // [b][e]
    __shared__ float fi_s[32][64];
    int h = blockIdx.x >> 6, m = blockIdx.x & 63;
    int tid = threadIdx.x;
    const u16* wr_p = wtre + ((size_t)(h * 64 + m)) * 4096;
    const u16* wi_p = wtim + ((size_t)(h * 64 + m)) * 4096;
    for (int i = tid; i < 4096; i += 256) {      // contiguous 8 KB each
        wr_s[i >> 6][i & 63] = b2f(wr_p[i]);
        wi_s[i >> 6][i & 63] = b2f(wi_p[i]);
    }
    const size_t KS = (size_t)32 * 65536;
    for (int i = tid; i < 2048; i += 256) {      // lane-contiguous in e
        int b = i >> 6, e = i & 63;
        size_t f0 = (size_t)b * 65536 + (size_t)m * 512 + h * 64 + e;
        size_t f1 = f0 + (size_t)64 * 512;
        fr_s[b][e] = ftT[f0] + ftT[f0 + KS] + ftT[f0 + 2 * KS] + ftT[f0 + 3 * KS];
        fi_s[b][e] = ftT[f1] + ftT[f1 + KS] + ftT[f1 + 2 * KS] + ftT[f1 + 3 * KS];
    }
    __syncthreads();
    int o = tid & 63, bg = tid >> 6;
    for (int bb = bg; bb < 32; bb += 4) {
        float accr = 0.f, acci = 0.f;
        #pragma unroll 8
        for (int e = 0; e < 64; ++e) {
            float wr = wr_s[e][o], wi = wi_s[e][o];
            float fr = fr_s[bb][e], fi = fi_s[bb][e];
            accr += fr * wr - fi * wi;
            acci += fr * wi + fi * wr;
        }
        size_t base = (((size_t)(bb * 8 + h)) * 64 + o) * 128;
        acat[base + m]      = f2b(accr);
        acat[base + 64 + m] = f2b(acci);
    }
}

// ---------------------------------------------------------------------------
// moving-average decomp residual, rolling-window float2 form:
// thread owns TWO d-columns over a 64-long l-segment; window sum updated
// incrementally; 8B loads, packed 4B bf16 writes. grid (32 b, 16 lseg).
// ---------------------------------------------------------------------------
__global__ void k_madiff(const float* __restrict__ in, float* __restrict__ out,
                         u16* __restrict__ out16) {
    int b = blockIdx.x, ls = blockIdx.y;
    int d2 = threadIdx.x;                 // float2 column index, 0..255
    const float2* base = (const float2*)(in + (size_t)b * 524288) + d2;
    int l0 = ls * 64;
    float sx = 0.f, sy = 0.f;
    #pragma unroll
    for (int k = -12; k <= 12; ++k) {
        int ll = l0 + k;
        ll = ll < 0 ? 0 : (ll > 1023 ? 1023 : ll);
        float2 v = base[(size_t)ll * 256];
        sx += v.x; sy += v.y;
    }
    for (int li = 0; li < 64; ++li) {
        int l = l0 + li;
        float2 x = base[(size_t)l * 256];
        float vx = x.x - sx * (1.f / 25.f);
        float vy = x.y - sy * (1.f / 25.f);
        size_t o = (size_t)b * 262144 + (size_t)l * 256 + d2;   // float2 index
        ((float2*)out)[o] = float2{vx, vy};
        unsigned pk = (unsigned)f2b(vx) | ((unsigned)f2b(vy) << 16);
        ((unsigned*)out16)[o] = pk;
        int lp = l + 13; lp = lp > 1023 ? 1023 : lp;
        int lm = l - 12; lm = lm < 0 ? 0 : lm;
        float2 a = base[(size_t)lp * 256];
        float2 s = base[(size_t)lm * 256];
        sx += a.x - s.x; sy += a.y - s.y;
    }
}

// ---------------------------------------------------------------------------
// LayerNorm over last dim (512)
// ---------------------------------------------------------------------------
__global__ void k_layernorm(const float* __restrict__ in, const float* __restrict__ g,
                            const float* __restrict__ bta, float* __restrict__ out) {
    int row = blockIdx.x;
    int tid = threadIdx.x;
    const float* r = in + (size_t)row * 512;
    float v0 = r[tid], v1 = r[tid + 256];
    float s = v0 + v1, s2 = v0 * v0 + v1 * v1;
    #pragma unroll
    for (int off = 32; off; off >>= 1) {
        s  += __shfl_down(s, off);
        s2 += __shfl_down(s2, off);
    }
    __shared__ float ws[4], ws2[4];
    if ((tid & 63) == 0) { ws[tid >> 6] = s; ws2[tid >> 6] = s2; }
    __syncthreads();
    if (tid == 0) {
        ws[0]  = ws[0] + ws[1] + ws[2] + ws[3];
        ws2[0] = ws2[0] + ws2[1] + ws2[2] + ws2[3];
    }
    __syncthreads();
    float mu = ws[0] * (1.f / 512.f);
    float var = ws2[0] * (1.f / 512.f) - mu * mu;
    float rs = rsqrtf(var + 1e-5f);
    float* o = out + (size_t)row * 512;
    o[tid]       = (v0 - mu) * rs * g[tid]       + bta[tid];
    o[tid + 256] = (v1 - mu) * rs * g[tid + 256] + bta[tid + 256];
}

// Fused head LN + regression partial: per row, LayerNorm then dot with the
// matching reg_w slice -> partial[row].
__global__ void k_lnreg(const float* __restrict__ in, const float* __restrict__ g,
                        const float* __restrict__ bta, const float* __restrict__ rw,
                        float* __restrict__ partial) {
    int row = blockIdx.x;                 // b*1024 + l
    int tid = threadIdx.x;
    const float* r = in + (size_t)row * 512;
    float v0 = r[tid], v1 = r[tid + 256];
    float s = v0 + v1, s2 = v0 * v0 + v1 * v1;
    #pragma unroll
    for (int off = 32; off; off >>= 1) {
        s  += __shfl_down(s, off);
        s2 += __shfl_down(s2, off);
    }
    __shared__ float ws[4], ws2[4];
    if ((tid & 63) == 0) { ws[tid >> 6] = s; ws2[tid >> 6] = s2; }
    __syncthreads();
    if (tid == 0) {
        ws[0]  = ws[0] + ws[1] + ws[2] + ws[3];
        ws2[0] = ws2[0] + ws2[1] + ws2[2] + ws2[3];
    }
    __syncthreads();
    float mu = ws[0] * (1.f / 512.f);
    float var = ws2[0] * (1.f / 512.f) - mu * mu;
    float rs = rsqrtf(var + 1e-5f);
    const float* wrow = rw + (size_t)(row & 1023) * 512;
    float y0 = (v0 - mu) * rs * g[tid]       + bta[tid];
    float y1 = (v1 - mu) * rs * g[tid + 256] + bta[tid + 256];
    float p = y0 * wrow[tid] + y1 * wrow[tid + 256];
    #pragma unroll
    for (int off = 32; off; off >>= 1) p += __shfl_down(p, off);
    __shared__ float wp[4];
    if ((tid & 63) == 0) wp[tid >> 6] = p;
    __syncthreads();
    if (tid == 0) partial[row] = wp[0] + wp[1] + wp[2] + wp[3];
}

// out[b] = sum_l partial[b*1024+l] + reg_b (deterministic fixed-order tree)
__global__ void k_regf2(const float* __restrict__ partial, const float* __restrict__ rb,
                        float* __restrict__ out) {
    int b = blockIdx.x;
    int tid = threadIdx.x;
    const float* p = partial + (size_t)b * 1024;
    float s = p[tid] + p[tid + 256] + p[tid + 512] + p[tid + 768];
    #pragma unroll
    for (int off = 32; off; off >>= 1) s += __shfl_down(s, off);
    __shared__ float ws[4];
    if ((tid & 63) == 0) ws[tid >> 6] = s;
    __syncthreads();
    if (tid == 0) out[b] = ws[0] + ws[1] + ws[2] + ws[3] + rb[0];
}

// column-mean phase 1: partial[b][seg][d] = sum over 128 l's
__global__ __launch_bounds__(512) void k_colmean1(const float* __restrict__ in,
                                                  float* __restrict__ part) {
    int b = blockIdx.x, seg = blockIdx.y;   // 32 x 8
    int d = threadIdx.x;                    // 512
    const float* p = in + ((size_t)b * 1024 + seg * 128) * 512 + d;
    float s = 0.f;
    for (int l = 0; l < 128; ++l) s += p[(size_t)l * 512];
    part[((size_t)b * 8 + seg) * 512 + d] = s;
}

// column-mean phase 2: mean[b][d] = (sum over 8 segs) / 1024
__global__ void k_colmean2(const float* __restrict__ part, float* __restrict__ mean) {
    int i = blockIdx.x * 256 + threadIdx.x;   // 16384
    int b = i >> 9, d = i & 511;
    float s = 0.f;
    #pragma unroll
    for (int seg = 0; seg < 8; ++seg) s += part[((size_t)b * 8 + seg) * 512 + d];
    mean[i] = s * (1.f / 1024.f);
}

// subtract per-(b,d) mean, write fp32 in place + bf16 mirror
__global__ void k_subcol(float* __restrict__ x, const float* __restrict__ mean,
                         u16* __restrict__ x16) {
    int idx = blockIdx.x * 256 + threadIdx.x;
    int d = idx & 511;
    int b = idx >> 19;
    float v = x[idx] - mean[b * 512 + d];
    x[idx] = v;
    x16[idx] = f2b(v);
}

// ---------------------------------------------------------------------------
extern "C" void kernel_launch(void* const* d_in, const int* in_sizes, int n_in,
                              void* d_out, int out_size, void* d_ws, size_t ws_size,
                              hipStream_t stream) {
    const float* x_enc  = (const float*)d_in[0];
    const float* conv_w = (const float*)d_in[1];
    const float* wq     = (const float*)d_in[2];
    const float* bq     = (const float*)d_in[3];
    const float* wo     = (const float*)d_in[4];
    const float* bo     = (const float*)d_in[5];
    const float* fw_re  = (const float*)d_in[6];
    const float* fw_im  = (const float*)d_in[7];
    const float* c1w    = (const float*)d_in[8];
    const float* c2w    = (const float*)d_in[9];
    const float* enc_g  = (const float*)d_in[10];
    const float* enc_b  = (const float*)d_in[11];
    const float* ff_w   = (const float*)d_in[12];
    const float* ff_b   = (const float*)d_in[13];
    const float* ffn_g  = (const float*)d_in[14];
    const float* ffn_b  = (const float*)d_in[15];
    const float* reg_w  = (const float*)d_in[16];
    const float* reg_b  = (const float*)d_in[17];
    float* out = (float*)d_out;

    // ---- workspace layout (byte offsets; total 227,606,528 B ≈ 227.6 MB) ----
    char* wsb = (char*)d_ws;
    float* F0    = (float*)(wsb);                        // 64 MiB fp32 [B,L,D]
    float* F1    = (float*)(wsb + 67108864);             // 64 MiB fp32 / y16 / ftt partials
    u16*   A16   = (u16*)  (wsb + 134217728);            // 32 MiB bf16 [B,L,D] (x mirror)
    u16*   U16   = (u16*)  (wsb + 167772160);            // 32 MiB bf16 (qT [512][32768] / new_x)
    u16*   AC16  = (u16*)  (wsb + 201326592);            // 4 MiB  bf16 [16384][128]
    float* FTT   = (float*)(wsb + 205520896);            // 8 MiB: WT16 re+im during layers; head partials after
    float* PE    = (float*)(wsb + 213909504);            // 2 MiB  fp32 [1024][512]
    u16*   TRIG  = (u16*)  (wsb + 216006656);            // 256 KiB [128][1024]
    u16*   TCAT  = (u16*)  (wsb + 216268800);            // 256 KiB [1024][128]
    u16*   WQ16  = (u16*)  (wsb + 216530944);            // 1 MiB [2][512][512]
    u16*   WO16  = (u16*)  (wsb + 217579520);            // 1 MiB
    u16*   C1W16 = (u16*)  (wsb + 218628096);            // 4 MiB [2][2048][512]
    u16*   C2W16 = (u16*)  (wsb + 222822400);            // 4 MiB [2][512][2048]
    u16*   FFW16 = (u16*)  (wsb + 227016704);            // 512 KiB
    float* CMEAN = (float*)(wsb + 227540992);            // 64 KiB
    const size_t need_bytes = 227606528;
    if (ws_size < need_bytes) return;   // clean diagnostic failure

    u16* WTRE16 = (u16*)FTT;             // 4 MiB [8][64][4096] bf16 (per-layer)
    u16* WTIM16 = WTRE16 + 2097152;      // 4 MiB

    const int BLD = B_ * L_ * D_;
    dim3 blk(256);

    // tables + weight casts + embedding
    k_tables<<<2048, blk, 0, stream>>>(TRIG, TCAT, PE);
    k_cast<<<512,  blk, 0, stream>>>(wq,   WQ16,  524288 / 4);
    k_cast<<<512,  blk, 0, stream>>>(wo,   WO16,  524288 / 4);
    k_cast<<<2048, blk, 0, stream>>>(c1w,  C1W16, 2097152 / 4);
    k_cast<<<2048, blk, 0, stream>>>(c2w,  C2W16, 2097152 / 4);
    k_cast<<<256,  blk, 0, stream>>>(ff_w, FFW16, 262144 / 4);
    k_embed<<<dim3(64, 32), 512, 0, stream>>>(x_enc, conv_w, PE, F0, A16);

    float* cur = F0;
    float* alt = F1;
    const dim3 g_big(4, 256);     // M=32768, N=512

    for (int l = 0; l < 2; ++l) {
        const float* bq_l = bq + l * 512;
        const float* bo_l = bo + l * 512;
        const u16* wo16_l = WO16 + (size_t)l * 262144;
        const u16* c1_l   = C1W16 + (size_t)l * DFF_ * D_;
        const u16* c2_l   = C2W16 + (size_t)l * D_ * DFF_;
        const float* fwre_l = fw_re + (size_t)l * H_ * E_ * E_ * M_;
        const float* fwim_l = fw_im + (size_t)l * H_ * E_ * E_ * M_;

        // transpose+cast fourier weights for this layer -> WT16 (coalesced)
        k_wtrans<<<dim3(64, 8, 2), blk, 0, stream>>>(fwre_l, fwim_l, WTRE16, WTIM16);
        // qT[c][b*1024+l] = wq @ x^T + bq  (swapped operands, direct bf16)
        k_mfma<false, true, false, false, false, true><<<dim3(256, 4), blk, 0, stream>>>(
            WQ16 + (size_t)l * 262144, A16, bq_l, nullptr, nullptr, U16,
            512, 512, 512, 32768, 0, 0);
        // forward DFT, transposed output + K-split x4:
        // partials [z=ks*32+b][128 mc][512 c] -> alt (dead until madiff)
        float* ftt4 = alt;
        k_mfma<false, false, false, false, true, false, true>
            <<<dim3(4, 1, 128), blk, 0, stream>>>(
            TRIG, U16, nullptr, nullptr, ftt4, nullptr,
            256, 1024, 32768, 512, 0, 0);
        // complex mode mixing (sums 4 K-slice partials; coalesced reads) -> AC16
        k_modemix<<<512, blk, 0, stream>>>(ftt4, WTRE16, WTIM16, AC16);
        // inverse DFT as GEMM -> U16 = new_x bf16 [B,H,E,L]
        k_mfma<false, false, false, false, false, true><<<dim3(8, 128), blk, 0, stream>>>(
            AC16, TCAT, nullptr, nullptr, nullptr, U16, 128, 128, 128, 1024, 0, 0);
        // x = x + (new_x @ wo^T + bo) -> cur (in-place add)
        k_mfma<true, false, false, true, true, false><<<g_big, blk, 0, stream>>>(
            U16, wo16_l, bo_l, cur, cur, nullptr, 512, 512, 512, 512, 0, 0);
        // x = x - ma(x) -> alt fp32 + A16 bf16 ; swap
        k_madiff<<<dim3(32, 16), blk, 0, stream>>>(cur, alt, A16);
        { float* t = cur; cur = alt; alt = t; }
        // FFN: 2 serial M-chunks of 16384 rows, full DFF per chunk.
        u16* y16 = (u16*)alt;
        for (int c = 0; c < 2; ++c) {
            const size_t aoff = (size_t)c * 16384 * 512;
            k_mfma<false, false, true, false, false, true><<<dim3(16, 128), blk, 0, stream>>>(
                A16 + aoff, c1_l, nullptr, nullptr, nullptr, y16,
                512, 512, 512, 2048, 0, 0);
            k_mfma<false, false, false, true, true, false><<<dim3(4, 128), blk, 0, stream>>>(
                y16, c2_l, nullptr, cur + aoff, cur + aoff, nullptr,
                2048, 2048, 2048, 512, 0, 0);
        }
        // x = xy - ma(xy) -> alt + A16 ; swap
        k_madiff<<<dim3(32, 16), blk, 0, stream>>>(cur, alt, A16);
        { float* t = cur; cur = alt; alt = t; }
    }

    // my_Layernorm: LN then subtract per-(b,d) mean over L
    k_layernorm<<<32768, blk, 0, stream>>>(cur, enc_g, enc_b, alt);
    k_colmean1<<<dim3(B_, 8), 512, 0, stream>>>(alt, FTT);
    k_colmean2<<<64, blk, 0, stream>>>(FTT, CMEAN);
    k_subcol<<<BLD / 256, blk, 0, stream>>>(alt, CMEAN, A16);
    // head Linear -> cur, then fused LN+regression
    k_mfma<true, false, false, false, true, false><<<g_big, blk, 0, stream>>>(
        A16, FFW16, ff_b, nullptr, cur, nullptr, 512, 512, 512, 512, 0, 0);
    k_lnreg<<<32768, blk, 0, stream>>>(cur, ffn_g, ffn_b, reg_w, FTT);
    k_regf2<<<32, blk, 0, stream>>>(FTT, reg_b, out);
}

// Round 14
// 1188.634 us; speedup vs baseline: 1.0479x; 1.0479x over previous
//
#include <hip/hip_runtime.h>
#include <math.h>

static constexpr int B_   = 32;
static constexpr int L_   = 1024;
static constexpr int CIN_ = 21;
static constexpr int D_   = 512;
static constexpr int H_   = 8;
static constexpr int E_   = 64;
static constexpr int DFF_ = 2048;
static constexpr int M_   = 64;   // MODES

typedef unsigned short u16;
typedef __attribute__((ext_vector_type(8))) short bf16x8;
typedef __attribute__((ext_vector_type(4))) float f32x4;
typedef __attribute__((ext_vector_type(4))) unsigned short u16x4;

// RNE float->bf16 (bit-level, no header dependency)
static __device__ __forceinline__ u16 f2b(float f) {
    unsigned u = __float_as_uint(f);
    unsigned r = (u + 0x7fffu + ((u >> 16) & 1u)) >> 16;
    return (u16)r;
}
static __device__ __forceinline__ float b2f(u16 x) {
    return __uint_as_float((unsigned)x << 16);
}

// async global->LDS 16B/lane copy (CK-style int-roundtrip AS casts;
// LDS dest is wave-uniform, lanes land at base + lane*16)
static __device__ __forceinline__ void gload16(const u16* g, u16* l) {
    unsigned long long ga = (unsigned long long)g;
    unsigned la = (unsigned)(unsigned long long)l;   // low 32 bits = LDS offset
    __builtin_amdgcn_global_load_lds(
        (const __attribute__((address_space(1))) void*)ga,
        (__attribute__((address_space(3))) void*)(unsigned long long)la,
        16, 0, 0);
}

// ---------------------------------------------------------------------------
// Tables (fp32 trig): TRIG16 [128 mcat][1024 l] (rows 0-63 cos, 64-127 -sin);
// TCAT16 [1024][128] inverse-DFT coefficients (1/1024 baked in);
// PE fp32 [1024][512].
// ---------------------------------------------------------------------------
__global__ void k_tables(u16* trig, u16* tcat, float* pe) {
    int idx = blockIdx.x * 256 + threadIdx.x;   // 0 .. 524287
    if (idx < 131072) {                          // trig [mc][l]
        int l = idx & 1023, mc = idx >> 10;
        int m = mc & 63;
        float th = (float)((m * l) & 1023) * 0.006135923151542565f; // 2pi/1024
        float v = (mc < 64) ? cosf(th) : (-sinf(th));
        trig[idx] = f2b(v);
    }
    if (idx < 131072) {                          // tcat [l][k]
        int k = idx & 127, l = idx >> 7;
        int m = k & 63;
        float th = (float)((m * l) & 1023) * 0.006135923151542565f;
        float v;
        if (k < 64) v = (m == 0) ? 1.0f : (2.0f * cosf(th));
        else        v = (m == 0) ? 0.0f : (-2.0f * sinf(th));
        tcat[idx] = f2b(v * (1.0f / 1024.0f));
    }
    if (idx < 524288) {                          // pe [l][d]
        int d = idx & 511, l = idx >> 9;
        int i2 = d >> 1;
        float div = expf(-(float)(2 * i2) * 0.017988946039015984f);
        float arg = (float)l * div;
        pe[idx] = (d & 1) ? cosf(arg) : sinf(arg);
    }
}

// generic fp32 -> bf16 cast (n multiple of 4)
__global__ void k_cast(const float* __restrict__ in, u16* __restrict__ out, int n4) {
    int i = blockIdx.x * 256 + threadIdx.x;
    if (i < n4) {
        float4 v = ((const float4*)in)[i];
        u16x4 o = { f2b(v.x), f2b(v.y), f2b(v.z), f2b(v.w) };
        ((u16x4*)out)[i] = o;
    }
}

// ---------------------------------------------------------------------------
// Fourier-weight transpose: [h][e][o][m] fp32 -> [h][m][e*64+o] bf16.
// LDS-tiled, both sides coalesced. grid (64 eo-tiles, 8 h, 2 re/im).
// ---------------------------------------------------------------------------
__global__ void k_wtrans(const float* __restrict__ re, const float* __restrict__ im,
                         u16* __restrict__ outre, u16* __restrict__ outim) {
    __shared__ float t[64][65];
    const float* src = blockIdx.z ? im : re;
    u16* dst = blockIdx.z ? outim : outre;
    int h = blockIdx.y, eo0 = blockIdx.x * 64;
    int j = threadIdx.x & 63, i0 = threadIdx.x >> 6;
    for (int i = i0; i < 64; i += 4)
        t[i][j] = src[(size_t)h * 262144 + (size_t)(eo0 + i) * 64 + j];
    __syncthreads();
    for (int i = i0; i < 64; i += 4)
        dst[(size_t)h * 262144 + (size_t)i * 4096 + eo0 + j] = f2b(t[j][i]);
}

// ---------------------------------------------------------------------------
// Embedding: circular conv1d(k=3) + PE table. Block = 512 threads (one per d),
// 32 l-values per thread; x_enc strip in LDS; rolling 2-row register window.
// (round-12 form — the 16-l split regressed weight-load amortization)
// ---------------------------------------------------------------------------
__global__ __launch_bounds__(512) void k_embed(
        const float* __restrict__ xe, const float* __restrict__ cw,
        const float* __restrict__ pe, float* __restrict__ x32,
        u16* __restrict__ x16) {
    __shared__ float strip[34][21];
    int b = blockIdx.y, l0 = blockIdx.x * 32;
    int d = threadIdx.x;
    for (int i = d; i < 34 * 21; i += 512) {
        int r = i / 21, c = i - r * 21;
        int ls = (l0 + r - 1 + 1024) & 1023;
        strip[r][c] = xe[((size_t)b * 1024 + ls) * 21 + c];
    }
    __syncthreads();
    float w[3][21];
    #pragma unroll
    for (int k = 0; k < 3; ++k)
        #pragma unroll
        for (int c = 0; c < 21; ++c)
            w[k][c] = cw[(size_t)d * 63 + c * 3 + k];
    float a0[21], a1[21];
    #pragma unroll
    for (int c = 0; c < 21; ++c) { a0[c] = strip[0][c]; a1[c] = strip[1][c]; }
    for (int li = 0; li < 32; ++li) {
        float acc = 0.f;
        #pragma unroll
        for (int c = 0; c < 21; ++c) {
            float a2 = strip[li + 2][c];
            acc += w[0][c] * a0[c] + w[1][c] * a1[c] + w[2][c] * a2;
            a0[c] = a1[c]; a1[c] = a2;
        }
        int l = l0 + li;
        float v = acc + pe[(size_t)l * 512 + d];
        size_t o = ((size_t)b * 1024 + l) * 512 + d;
        x32[o] = v;
        x16[o] = f2b(v);
    }
}

// ---------------------------------------------------------------------------
// bf16 MFMA NT GEMM: 128x128 tile, 4 waves, 16x16x32 MFMA, BK=32 (round-12
// form — BK=64's 128B LDS rows hit m201's 16-way bank conflict and regressed),
// global_load_lds staging, 3 blocks/CU. BIAS per-col, BIASR per-row.
// DFTZ: transposed-output DFT mode — grid (4 c-tiles, 1, 128 z):
//   z = ks*32+b; A(=TRIG) += ks*256, W(=qT) += b*1024 + ks*256,
//   C partial at z*65536, layout [mc][c].
// ---------------------------------------------------------------------------
template<bool BIAS, bool BIASR, bool GELU, bool ADD, bool WF32, bool WBF16,
         bool DFTZ = false>
__global__ __launch_bounds__(256, 3) void k_mfma(
        const u16* __restrict__ A, const u16* __restrict__ W,
        const float* __restrict__ bias, const float* addp,
        float* C32, u16* C16,
        int K, int lda, int ldw, int ldc, long strideA, long strideC) {
    __shared__ __align__(16) u16 As[128 * 32];
    __shared__ __align__(16) u16 Bs[128 * 32];
    const int tid  = threadIdx.x;
    const int lane = tid & 63, wid = tid >> 6;
    int m0, n0;
    size_t cbase;
    if constexpr (DFTZ) {
        int z  = blockIdx.z;
        int ks = z >> 5;                     // K-slice 0..3
        m0 = 0;
        n0 = blockIdx.x * 128;
        A += (size_t)ks * 256;
        W += (size_t)(z & 31) * 1024 + (size_t)ks * 256;
        cbase = (size_t)z * 65536;
    } else {
        m0 = blockIdx.y * 128;
        n0 = blockIdx.x * 128;
        A += (size_t)blockIdx.z * strideA;
        cbase = (size_t)blockIdx.z * strideC;
    }

    // staging: wave wid owns rows [32*wid, 32*wid+32) of As/Bs (linear LDS).
    const int srow = lane >> 2, scol = (lane & 3) * 8;
    const u16* ga0 = A + (size_t)(m0 + wid * 32 + srow) * lda + scol;
    const u16* ga1 = ga0 + (size_t)16 * lda;
    const u16* gb0 = W + (size_t)(n0 + wid * 32 + srow) * ldw + scol;
    const u16* gb1 = gb0 + (size_t)16 * ldw;
    u16* la0 = &As[wid * 32 * 32];          // wave-uniform LDS bases
    u16* la1 = la0 + 16 * 32;
    u16* lb0 = &Bs[wid * 32 * 32];
    u16* lb1 = lb0 + 16 * 32;

    const int wr = wid >> 1, wc = wid & 1;
    const int fr = lane & 15, fg = lane >> 4;

    f32x4 acc[4][4];
    #pragma unroll
    for (int i = 0; i < 4; ++i)
        #pragma unroll
        for (int j = 0; j < 4; ++j)
            acc[i][j] = f32x4{0.f, 0.f, 0.f, 0.f};

    for (int k0 = 0; k0 < K; k0 += 32) {
        __syncthreads();                    // prev iter's ds_reads done
        gload16(ga0 + k0, la0);
        gload16(ga1 + k0, la1);
        gload16(gb0 + k0, lb0);
        gload16(gb1 + k0, lb1);
        __syncthreads();                    // vmcnt(0) drained -> tile ready
        bf16x8 af[4], bfr[4];
        #pragma unroll
        for (int i = 0; i < 4; ++i) {
            af[i]  = *(const bf16x8*)&As[(wr * 64 + i * 16 + fr) * 32 + fg * 8];
            bfr[i] = *(const bf16x8*)&Bs[(wc * 64 + i * 16 + fr) * 32 + fg * 8];
        }
        #pragma unroll
        for (int i = 0; i < 4; ++i)
            #pragma unroll
            for (int j = 0; j < 4; ++j)
                acc[i][j] = __builtin_amdgcn_mfma_f32_16x16x32_bf16(
                    af[i], bfr[j], acc[i][j], 0, 0, 0);
    }

    #pragma unroll
    for (int i = 0; i < 4; ++i) {
        #pragma unroll
        for (int j = 0; j < 4; ++j) {
            #pragma unroll
            for (int r = 0; r < 4; ++r) {
                int row = m0 + wr * 64 + i * 16 + fg * 4 + r;
                int col = n0 + wc * 64 + j * 16 + fr;
                float v = acc[i][j][r];
                if (BIAS)  v += bias[col];
                if (BIASR) v += bias[row];
                if (GELU) v = 0.5f * v * (1.f + erff(v * 0.70710678118f));
                size_t o = cbase + (size_t)row * ldc + col;
                if (ADD)  v += addp[o];
                if (WF32) C32[o] = v;
                if (WBF16) C16[o] = f2b(v);
            }
        }
    }
}

// ---------------------------------------------------------------------------
// Complex per-mode channel mix. Inputs: ftt partials [z=ks*32+b][mc=128][c=512]
// (4 K-slices summed here, lane-contiguous in c) and transposed bf16 weights
// WT [h][m][e*64+o]. Output acat bf16 [B*H*64o][128] (Re | Im).
// grid 512 = (h,m), block 256.
// ---------------------------------------------------------------------------
__global__ void k_modemix(const float* __restrict__ ftT,
                          const u16* __restrict__ wtre, const u16* __restrict__ wtim,
                          u16* __restrict__ acat) {
    __shared__ float wr_s[64][64];   // [e][o]
    __shared__ float wi_s[64][64];
    __shared__ float fr_s[32][64];   // [b][e]
    __shared__ float fi_s[32][64];
    int h = blockIdx.x >> 6, m = blockIdx.x & 63;
    int tid = threadIdx.x;
    const u16* wr_p = wtre + ((size_t)(h * 64 + m)) * 4096;
    const u16* wi_p = wtim + ((size_t)(h * 64 + m)) * 4096;
    for (int i = tid; i < 4096; i += 256) {      // contiguous 8 KB each
        wr_s[i >> 6][i & 63] = b2f(wr_p[i]);
        wi_s[i >> 6][i & 63] = b2f(wi_p[i]);
    }
    const size_t KS = (size_t)32 * 65536;
    for (int i = tid; i < 2048; i += 256) {      // lane-contiguous in e
        int b = i >> 6, e = i & 63;
        size_t f0 = (size_t)b * 65536 + (size_t)m * 512 + h * 64 + e;
        size_t f1 = f0 + (size_t)64 * 512;
        fr_s[b][e] = ftT[f0] + ftT[f0 + KS] + ftT[f0 + 2 * KS] + ftT[f0 + 3 * KS];
        fi_s[b][e] = ftT[f1] + ftT[f1 + KS] + ftT[f1 + 2 * KS] + ftT[f1 + 3 * KS];
    }
    __syncthreads();
    int o = tid & 63, bg = tid >> 6;
    for (int bb = bg; bb < 32; bb += 4) {
        float accr = 0.f, acci = 0.f;
        #pragma unroll 8
        for (int e = 0; e < 64; ++e) {
            float wr = wr_s[e][o], wi = wi_s[e][o];
            float fr = fr_s[bb][e], fi = fi_s[bb][e];
            accr += fr * wr - fi * wi;
            acci += fr * wi + fi * wr;
        }
        size_t base = (((size_t)(bb * 8 + h)) * 64 + o) * 128;
        acat[base + m]      = f2b(accr);
        acat[base + 64 + m] = f2b(acci);
    }
}

// ---------------------------------------------------------------------------
// moving-average decomp residual, rolling-window float2 form:
// thread owns TWO d-columns over a 64-long l-segment; window sum updated
// incrementally; 8B loads, packed 4B bf16 writes. grid (32 b, 16 lseg).
// ---------------------------------------------------------------------------
__global__ void k_madiff(const float* __restrict__ in, float* __restrict__ out,
                         u16* __restrict__ out16) {
    int b = blockIdx.x, ls = blockIdx.y;
    int d2 = threadIdx.x;                 // float2 column index, 0..255
    const float2* base = (const float2*)(in + (size_t)b * 524288) + d2;
    int l0 = ls * 64;
    float sx = 0.f, sy = 0.f;
    #pragma unroll
    for (int k = -12; k <= 12; ++k) {
        int ll = l0 + k;
        ll = ll < 0 ? 0 : (ll > 1023 ? 1023 : ll);
        float2 v = base[(size_t)ll * 256];
        sx += v.x; sy += v.y;
    }
    for (int li = 0; li < 64; ++li) {
        int l = l0 + li;
        float2 x = base[(size_t)l * 256];
        float vx = x.x - sx * (1.f / 25.f);
        float vy = x.y - sy * (1.f / 25.f);
        size_t o = (size_t)b * 262144 + (size_t)l * 256 + d2;   // float2 index
        ((float2*)out)[o] = float2{vx, vy};
        unsigned pk = (unsigned)f2b(vx) | ((unsigned)f2b(vy) << 16);
        ((unsigned*)out16)[o] = pk;
        int lp = l + 13; lp = lp > 1023 ? 1023 : lp;
        int lm = l - 12; lm = lm < 0 ? 0 : lm;
        float2 a = base[(size_t)lp * 256];
        float2 s = base[(size_t)lm * 256];
        sx += a.x - s.x; sy += a.y - s.y;
    }
}

// ---------------------------------------------------------------------------
// LayerNorm over last dim (512)
// ---------------------------------------------------------------------------
__global__ void k_layernorm(const float* __restrict__ in, const float* __restrict__ g,
                            const float* __restrict__ bta, float* __restrict__ out) {
    int row = blockIdx.x;
    int tid = threadIdx.x;
    const float* r = in + (size_t)row * 512;
    float v0 = r[tid], v1 = r[tid + 256];
    float s = v0 + v1, s2 = v0 * v0 + v1 * v1;
    #pragma unroll
    for (int off = 32; off; off >>= 1) {
        s  += __shfl_down(s, off);
        s2 += __shfl_down(s2, off);
    }
    __shared__ float ws[4], ws2[4];
    if ((tid & 63) == 0) { ws[tid >> 6] = s; ws2[tid >> 6] = s2; }
    __syncthreads();
    if (tid == 0) {
        ws[0]  = ws[0] + ws[1] + ws[2] + ws[3];
        ws2[0] = ws2[0] + ws2[1] + ws2[2] + ws2[3];
    }
    __syncthreads();
    float mu = ws[0] * (1.f / 512.f);
    float var = ws2[0] * (1.f / 512.f) - mu * mu;
    float rs = rsqrtf(var + 1e-5f);
    float* o = out + (size_t)row * 512;
    o[tid]       = (v0 - mu) * rs * g[tid]       + bta[tid];
    o[tid + 256] = (v1 - mu) * rs * g[tid + 256] + bta[tid + 256];
}

// Fused head LN + regression partial: per row, LayerNorm then dot with the
// matching reg_w slice -> partial[row].
__global__ void k_lnreg(const float* __restrict__ in, const float* __restrict__ g,
                        const float* __restrict__ bta, const float* __restrict__ rw,
                        float* __restrict__ partial) {
    int row = blockIdx.x;                 // b*1024 + l
    int tid = threadIdx.x;
    const float* r = in + (size_t)row * 512;
    float v0 = r[tid], v1 = r[tid + 256];
    float s = v0 + v1, s2 = v0 * v0 + v1 * v1;
    #pragma unroll
    for (int off = 32; off; off >>= 1) {
        s  += __shfl_down(s, off);
        s2 += __shfl_down(s2, off);
    }
    __shared__ float ws[4], ws2[4];
    if ((tid & 63) == 0) { ws[tid >> 6] = s; ws2[tid >> 6] = s2; }
    __syncthreads();
    if (tid == 0) {
        ws[0]  = ws[0] + ws[1] + ws[2] + ws[3];
        ws2[0] = ws2[0] + ws2[1] + ws2[2] + ws2[3];
    }
    __syncthreads();
    float mu = ws[0] * (1.f / 512.f);
    float var = ws2[0] * (1.f / 512.f) - mu * mu;
    float rs = rsqrtf(var + 1e-5f);
    const float* wrow = rw + (size_t)(row & 1023) * 512;
    float y0 = (v0 - mu) * rs * g[tid]       + bta[tid];
    float y1 = (v1 - mu) * rs * g[tid + 256] + bta[tid + 256];
    float p = y0 * wrow[tid] + y1 * wrow[tid + 256];
    #pragma unroll
    for (int off = 32; off; off >>= 1) p += __shfl_down(p, off);
    __shared__ float wp[4];
    if ((tid & 63) == 0) wp[tid >> 6] = p;
    __syncthreads();
    if (tid == 0) partial[row] = wp[0] + wp[1] + wp[2] + wp[3];
}

// out[b] = sum_l partial[b*1024+l] + reg_b (deterministic fixed-order tree)
__global__ void k_regf2(const float* __restrict__ partial, const float* __restrict__ rb,
                        float* __restrict__ out) {
    int b = blockIdx.x;
    int tid = threadIdx.x;
    const float* p = partial + (size_t)b * 1024;
    float s = p[tid] + p[tid + 256] + p[tid + 512] + p[tid + 768];
    #pragma unroll
    for (int off = 32; off; off >>= 1) s += __shfl_down(s, off);
    __shared__ float ws[4];
    if ((tid & 63) == 0) ws[tid >> 6] = s;
    __syncthreads();
    if (tid == 0) out[b] = ws[0] + ws[1] + ws[2] + ws[3] + rb[0];
}

// column-mean phase 1: partial[b][seg][d] = sum over 128 l's
__global__ __launch_bounds__(512) void k_colmean1(const float* __restrict__ in,
                                                  float* __restrict__ part) {
    int b = blockIdx.x, seg = blockIdx.y;   // 32 x 8
    int d = threadIdx.x;                    // 512
    const float* p = in + ((size_t)b * 1024 + seg * 128) * 512 + d;
    float s = 0.f;
    for (int l = 0; l < 128; ++l) s += p[(size_t)l * 512];
    part[((size_t)b * 8 + seg) * 512 + d] = s;
}

// column-mean phase 2: mean[b][d] = (sum over 8 segs) / 1024
__global__ void k_colmean2(const float* __restrict__ part, float* __restrict__ mean) {
    int i = blockIdx.x * 256 + threadIdx.x;   // 16384
    int b = i >> 9, d = i & 511;
    float s = 0.f;
    #pragma unroll
    for (int seg = 0; seg < 8; ++seg) s += part[((size_t)b * 8 + seg) * 512 + d];
    mean[i] = s * (1.f / 1024.f);
}

// subtract per-(b,d) mean, write fp32 in place + bf16 mirror
__global__ void k_subcol(float* __restrict__ x, const float* __restrict__ mean,
                         u16* __restrict__ x16) {
    int idx = blockIdx.x * 256 + threadIdx.x;
    int d = idx & 511;
    int b = idx >> 19;
    float v = x[idx] - mean[b * 512 + d];
    x[idx] = v;
    x16[idx] = f2b(v);
}

// ---------------------------------------------------------------------------
extern "C" void kernel_launch(void* const* d_in, const int* in_sizes, int n_in,
                              void* d_out, int out_size, void* d_ws, size_t ws_size,
                              hipStream_t stream) {
    const float* x_enc  = (const float*)d_in[0];
    const float* conv_w = (const float*)d_in[1];
    const float* wq     = (const float*)d_in[2];
    const float* bq     = (const float*)d_in[3];
    const float* wo     = (const float*)d_in[4];
    const float* bo     = (const float*)d_in[5];
    const float* fw_re  = (const float*)d_in[6];
    const float* fw_im  = (const float*)d_in[7];
    const float* c1w    = (const float*)d_in[8];
    const float* c2w    = (const float*)d_in[9];
    const float* enc_g  = (const float*)d_in[10];
    const float* enc_b  = (const float*)d_in[11];
    const float* ff_w   = (const float*)d_in[12];
    const float* ff_b   = (const float*)d_in[13];
    const float* ffn_g  = (const float*)d_in[14];
    const float* ffn_b  = (const float*)d_in[15];
    const float* reg_w  = (const float*)d_in[16];
    const float* reg_b  = (const float*)d_in[17];
    float* out = (float*)d_out;

    // ---- workspace layout (byte offsets; total 227,606,528 B ≈ 227.6 MB) ----
    char* wsb = (char*)d_ws;
    float* F0    = (float*)(wsb);                        // 64 MiB fp32 [B,L,D]
    float* F1    = (float*)(wsb + 67108864);             // 64 MiB fp32 / y16 / ftt partials
    u16*   A16   = (u16*)  (wsb + 134217728);            // 32 MiB bf16 [B,L,D] (x mirror)
    u16*   U16   = (u16*)  (wsb + 167772160);            // 32 MiB bf16 (qT [512][32768] / new_x)
    u16*   AC16  = (u16*)  (wsb + 201326592);            // 4 MiB  bf16 [16384][128]
    float* FTT   = (float*)(wsb + 205520896);            // 8 MiB: WT16 re+im during layers; head partials after
    float* PE    = (float*)(wsb + 213909504);            // 2 MiB  fp32 [1024][512]
    u16*   TRIG  = (u16*)  (wsb + 216006656);            // 256 KiB [128][1024]
    u16*   TCAT  = (u16*)  (wsb + 216268800);            // 256 KiB [1024][128]
    u16*   WQ16  = (u16*)  (wsb + 216530944);            // 1 MiB [2][512][512]
    u16*   WO16  = (u16*)  (wsb + 217579520);            // 1 MiB
    u16*   C1W16 = (u16*)  (wsb + 218628096);            // 4 MiB [2][2048][512]
    u16*   C2W16 = (u16*)  (wsb + 222822400);            // 4 MiB [2][512][2048]
    u16*   FFW16 = (u16*)  (wsb + 227016704);            // 512 KiB
    float* CMEAN = (float*)(wsb + 227540992);            // 64 KiB
    const size_t need_bytes = 227606528;
    if (ws_size < need_bytes) return;   // clean diagnostic failure

    u16* WTRE16 = (u16*)FTT;             // 4 MiB [8][64][4096] bf16 (per-layer)
    u16* WTIM16 = WTRE16 + 2097152;      // 4 MiB

    const int BLD = B_ * L_ * D_;
    dim3 blk(256);

    // tables + weight casts + embedding
    k_tables<<<2048, blk, 0, stream>>>(TRIG, TCAT, PE);
    k_cast<<<512,  blk, 0, stream>>>(wq,   WQ16,  524288 / 4);
    k_cast<<<512,  blk, 0, stream>>>(wo,   WO16,  524288 / 4);
    k_cast<<<2048, blk, 0, stream>>>(c1w,  C1W16, 2097152 / 4);
    k_cast<<<2048, blk, 0, stream>>>(c2w,  C2W16, 2097152 / 4);
    k_cast<<<256,  blk, 0, stream>>>(ff_w, FFW16, 262144 / 4);
    k_embed<<<dim3(32, 32), 512, 0, stream>>>(x_enc, conv_w, PE, F0, A16);

    float* cur = F0;
    float* alt = F1;
    const dim3 g_big(4, 256);     // M=32768, N=512

    for (int l = 0; l < 2; ++l) {
        const float* bq_l = bq + l * 512;
        const float* bo_l = bo + l * 512;
        const u16* wo16_l = WO16 + (size_t)l * 262144;
        const u16* c1_l   = C1W16 + (size_t)l * DFF_ * D_;
        const u16* c2_l   = C2W16 + (size_t)l * D_ * DFF_;
        const float* fwre_l = fw_re + (size_t)l * H_ * E_ * E_ * M_;
        const float* fwim_l = fw_im + (size_t)l * H_ * E_ * E_ * M_;

        // transpose+cast fourier weights for this layer -> WT16 (coalesced)
        k_wtrans<<<dim3(64, 8, 2), blk, 0, stream>>>(fwre_l, fwim_l, WTRE16, WTIM16);
        // qT[c][b*1024+l] = wq @ x^T + bq  (swapped operands, direct bf16)
        k_mfma<false, true, false, false, false, true><<<dim3(256, 4), blk, 0, stream>>>(
            WQ16 + (size_t)l * 262144, A16, bq_l, nullptr, nullptr, U16,
            512, 512, 512, 32768, 0, 0);
        // forward DFT, transposed output + K-split x4:
        // partials [z=ks*32+b][128 mc][512 c] -> alt (dead until madiff)
        float* ftt4 = alt;
        k_mfma<false, false, false, false, true, false, true>
            <<<dim3(4, 1, 128), blk, 0, stream>>>(
            TRIG, U16, nullptr, nullptr, ftt4, nullptr,
            256, 1024, 32768, 512, 0, 0);
        // complex mode mixing (sums 4 K-slice partials; coalesced reads) -> AC16
        k_modemix<<<512, blk, 0, stream>>>(ftt4, WTRE16, WTIM16, AC16);
        // inverse DFT as GEMM -> U16 = new_x bf16 [B,H,E,L]
        k_mfma<false, false, false, false, false, true><<<dim3(8, 128), blk, 0, stream>>>(
            AC16, TCAT, nullptr, nullptr, nullptr, U16, 128, 128, 128, 1024, 0, 0);
        // x = x + (new_x @ wo^T + bo) -> cur (in-place add)
        k_mfma<true, false, false, true, true, false><<<g_big, blk, 0, stream>>>(
            U16, wo16_l, bo_l, cur, cur, nullptr, 512, 512, 512, 512, 0, 0);
        // x = x - ma(x) -> alt fp32 + A16 bf16 ; swap
        k_madiff<<<dim3(32, 16), blk, 0, stream>>>(cur, alt, A16);
        { float* t = cur; cur = alt; alt = t; }
        // FFN: 2 serial M-chunks of 16384 rows, full DFF per chunk.
        u16* y16 = (u16*)alt;
        for (int c = 0; c < 2; ++c) {
            const size_t aoff = (size_t)c * 16384 * 512;
            k_mfma<false, false, true, false, false, true><<<dim3(16, 128), blk, 0, stream>>>(
                A16 + aoff, c1_l, nullptr, nullptr, nullptr, y16,
                512, 512, 512, 2048, 0, 0);
            k_mfma<false, false, false, true, true, false><<<dim3(4, 128), blk, 0, stream>>>(
                y16, c2_l, nullptr, cur + aoff, cur + aoff, nullptr,
                2048, 2048, 2048, 512, 0, 0);
        }
        // x = xy - ma(xy) -> alt + A16 ; swap
        k_madiff<<<dim3(32, 16), blk, 0, stream>>>(cur, alt, A16);
        { float* t = cur; cur = alt; alt = t; }
    }

    // my_Layernorm: LN then subtract per-(b,d) mean over L
    k_layernorm<<<32768, blk, 0, stream>>>(cur, enc_g, enc_b, alt);
    k_colmean1<<<dim3(B_, 8), 512, 0, stream>>>(alt, FTT);
    k_colmean2<<<64, blk, 0, stream>>>(FTT, CMEAN);
    k_subcol<<<BLD / 256, blk, 0, stream>>>(alt, CMEAN, A16);
    // head Linear -> cur, then fused LN+regression
    k_mfma<true, false, false, false, true, false><<<g_big, blk, 0, stream>>>(
        A16, FFW16, ff_b, nullptr, cur, nullptr, 512, 512, 512, 512, 0, 0);
    k_lnreg<<<32768, blk, 0, stream>>>(cur, ffn_g, ffn_b, reg_w, FTT);
    k_regf2<<<32, blk, 0, stream>>>(FTT, reg_b, out);
}

// Round 15
// 1095.892 us; speedup vs baseline: 1.1366x; 1.0846x over previous
//
#include <hip/hip_runtime.h>
#include <math.h>

static constexpr int B_   = 32;
static constexpr int L_   = 1024;
static constexpr int CIN_ = 21;
static constexpr int D_   = 512;
static constexpr int H_   = 8;
static constexpr int E_   = 64;
static constexpr int DFF_ = 2048;
static constexpr int M_   = 64;   // MODES

typedef unsigned short u16;
typedef __attribute__((ext_vector_type(8))) short bf16x8;
typedef __attribute__((ext_vector_type(4))) float f32x4;
typedef __attribute__((ext_vector_type(4))) unsigned short u16x4;

// RNE float->bf16 (bit-level, no header dependency)
static __device__ __forceinline__ u16 f2b(float f) {
    unsigned u = __float_as_uint(f);
    unsigned r = (u + 0x7fffu + ((u >> 16) & 1u)) >> 16;
    return (u16)r;
}
static __device__ __forceinline__ float b2f(u16 x) {
    return __uint_as_float((unsigned)x << 16);
}

// async global->LDS 16B/lane copy (CK-style int-roundtrip AS casts;
// LDS dest is wave-uniform, lanes land at base + lane*16)
static __device__ __forceinline__ void gload16(const u16* g, u16* l) {
    unsigned long long ga = (unsigned long long)g;
    unsigned la = (unsigned)(unsigned long long)l;   // low 32 bits = LDS offset
    __builtin_amdgcn_global_load_lds(
        (const __attribute__((address_space(1))) void*)ga,
        (__attribute__((address_space(3))) void*)(unsigned long long)la,
        16, 0, 0);
}

// ---------------------------------------------------------------------------
// Tables (fp32 trig): TRIG16 [128 mcat][1024 l] (rows 0-63 cos, 64-127 -sin);
// TCAT16 [1024][128] inverse-DFT coefficients (1/1024 baked in);
// PE fp32 [1024][512].
// ---------------------------------------------------------------------------
__global__ void k_tables(u16* trig, u16* tcat, float* pe) {
    int idx = blockIdx.x * 256 + threadIdx.x;   // 0 .. 524287
    if (idx < 131072) {                          // trig [mc][l]
        int l = idx & 1023, mc = idx >> 10;
        int m = mc & 63;
        float th = (float)((m * l) & 1023) * 0.006135923151542565f; // 2pi/1024
        float v = (mc < 64) ? cosf(th) : (-sinf(th));
        trig[idx] = f2b(v);
    }
    if (idx < 131072) {                          // tcat [l][k]
        int k = idx & 127, l = idx >> 7;
        int m = k & 63;
        float th = (float)((m * l) & 1023) * 0.006135923151542565f;
        float v;
        if (k < 64) v = (m == 0) ? 1.0f : (2.0f * cosf(th));
        else        v = (m == 0) ? 0.0f : (-2.0f * sinf(th));
        tcat[idx] = f2b(v * (1.0f / 1024.0f));
    }
    if (idx < 524288) {                          // pe [l][d]
        int d = idx & 511, l = idx >> 9;
        int i2 = d >> 1;
        float div = expf(-(float)(2 * i2) * 0.017988946039015984f);
        float arg = (float)l * div;
        pe[idx] = (d & 1) ? cosf(arg) : sinf(arg);
    }
}

// generic fp32 -> bf16 cast (n multiple of 4)
__global__ void k_cast(const float* __restrict__ in, u16* __restrict__ out, int n4) {
    int i = blockIdx.x * 256 + threadIdx.x;
    if (i < n4) {
        float4 v = ((const float4*)in)[i];
        u16x4 o = { f2b(v.x), f2b(v.y), f2b(v.z), f2b(v.w) };
        ((u16x4*)out)[i] = o;
    }
}

// ---------------------------------------------------------------------------
// Fourier-weight transpose: [h][e][o][m] fp32 -> [h][m][e*64+o] bf16.
// ---------------------------------------------------------------------------
__global__ void k_wtrans(const float* __restrict__ re, const float* __restrict__ im,
                         u16* __restrict__ outre, u16* __restrict__ outim) {
    __shared__ float t[64][65];
    const float* src = blockIdx.z ? im : re;
    u16* dst = blockIdx.z ? outim : outre;
    int h = blockIdx.y, eo0 = blockIdx.x * 64;
    int j = threadIdx.x & 63, i0 = threadIdx.x >> 6;
    for (int i = i0; i < 64; i += 4)
        t[i][j] = src[(size_t)h * 262144 + (size_t)(eo0 + i) * 64 + j];
    __syncthreads();
    for (int i = i0; i < 64; i += 4)
        dst[(size_t)h * 262144 + (size_t)i * 4096 + eo0 + j] = f2b(t[j][i]);
}

// ---------------------------------------------------------------------------
// im2col for embedding conv: A2[b*1024+l][kc] = xe[b][(l + kc%3 - 1) mod L][kc/3]
// (kc < 63; col 63 zero-padded). bf16 output, coalesced u16x4 writes.
// ---------------------------------------------------------------------------
__global__ void k_im2col(const float* __restrict__ xe, u16* __restrict__ a2) {
    int idx = blockIdx.x * 256 + threadIdx.x;    // 0 .. 524287 (32768*16)
    int row = idx >> 4, g = idx & 15;
    int b = row >> 10, l = row & 1023;
    u16x4 o;
    #pragma unroll
    for (int j = 0; j < 4; ++j) {
        int kc = g * 4 + j;
        float v = 0.f;
        if (kc < 63) {
            int c = kc / 3, k = kc - c * 3;
            int ls = (l + k - 1 + 1024) & 1023;
            v = xe[((size_t)b * 1024 + ls) * 21 + c];
        }
        o[j] = f2b(v);
    }
    *(u16x4*)(a2 + (size_t)row * 64 + g * 4) = o;
}

// conv weight pad+cast: w2[d][kc] = cw[d*63+kc] (kc<63), 0 at kc=63
__global__ void k_wpad(const float* __restrict__ cw, u16* __restrict__ w2) {
    int idx = blockIdx.x * 256 + threadIdx.x;   // 0..32767
    int d = idx >> 6, kc = idx & 63;
    float v = (kc < 63) ? cw[(size_t)d * 63 + kc] : 0.f;
    w2[idx] = f2b(v);
}

// ---------------------------------------------------------------------------
// bf16 MFMA NT GEMM: 128x128 tile, 4 waves, 16x16x32 MFMA, BK=64 staged as
// TWO split [128][32] buffers per operand (64B row pitch preserved -> no
// bank-conflict regression; barriers per unit K halved vs BK=32).
// global_load_lds staging, 3 blocks/CU. BIAS per-col, BIASR per-row.
// DFTZ: transposed-output DFT mode — grid (4 c-tiles, 1, 128 z).
// PEADD: epilogue adds addp[(row&1023)*512+col] (positional encoding).
// All K must be multiples of 64 (512/256/128/2048/64 here).
// ---------------------------------------------------------------------------
template<bool BIAS, bool BIASR, bool GELU, bool ADD, bool WF32, bool WBF16,
         bool DFTZ = false, bool PEADD = false>
__global__ __launch_bounds__(256, 3) void k_mfma(
        const u16* __restrict__ A, const u16* __restrict__ W,
        const float* __restrict__ bias, const float* addp,
        float* C32, u16* C16,
        int K, int lda, int ldw, int ldc, long strideA, long strideC) {
    __shared__ __align__(16) u16 As0[128 * 32];
    __shared__ __align__(16) u16 As1[128 * 32];
    __shared__ __align__(16) u16 Bs0[128 * 32];
    __shared__ __align__(16) u16 Bs1[128 * 32];
    const int tid  = threadIdx.x;
    const int lane = tid & 63, wid = tid >> 6;
    int m0, n0;
    size_t cbase;
    if constexpr (DFTZ) {
        int z  = blockIdx.z;
        int ks = z >> 5;                     // K-slice 0..3
        m0 = 0;
        n0 = blockIdx.x * 128;
        A += (size_t)ks * 256;
        W += (size_t)(z & 31) * 1024 + (size_t)ks * 256;
        cbase = (size_t)z * 65536;
    } else {
        m0 = blockIdx.y * 128;
        n0 = blockIdx.x * 128;
        A += (size_t)blockIdx.z * strideA;
        cbase = (size_t)blockIdx.z * strideC;
    }

    // staging: wave wid owns rows [32*wid, 32*wid+32); lane -> (row l>>2, col 8*(l&3))
    const int srow = lane >> 2, scol = (lane & 3) * 8;
    const u16* ga0 = A + (size_t)(m0 + wid * 32 + srow) * lda + scol;
    const u16* ga1 = ga0 + (size_t)16 * lda;
    const u16* gb0 = W + (size_t)(n0 + wid * 32 + srow) * ldw + scol;
    const u16* gb1 = gb0 + (size_t)16 * ldw;
    const int lofs0 = wid * 32 * 32, lofs1 = lofs0 + 16 * 32;

    const int wr = wid >> 1, wc = wid & 1;
    const int fr = lane & 15, fg = lane >> 4;

    f32x4 acc[4][4];
    #pragma unroll
    for (int i = 0; i < 4; ++i)
        #pragma unroll
        for (int j = 0; j < 4; ++j)
            acc[i][j] = f32x4{0.f, 0.f, 0.f, 0.f};

    for (int k0 = 0; k0 < K; k0 += 64) {
        __syncthreads();                    // prev iter's ds_reads done
        gload16(ga0 + k0,      &As0[lofs0]);
        gload16(ga1 + k0,      &As0[lofs1]);
        gload16(gb0 + k0,      &Bs0[lofs0]);
        gload16(gb1 + k0,      &Bs0[lofs1]);
        gload16(ga0 + k0 + 32, &As1[lofs0]);
        gload16(ga1 + k0 + 32, &As1[lofs1]);
        gload16(gb0 + k0 + 32, &Bs1[lofs0]);
        gload16(gb1 + k0 + 32, &Bs1[lofs1]);
        __syncthreads();                    // vmcnt(0) drained -> both halves ready
        {   // half 0
            bf16x8 af[4], bfr[4];
            #pragma unroll
            for (int i = 0; i < 4; ++i) {
                af[i]  = *(const bf16x8*)&As0[(wr * 64 + i * 16 + fr) * 32 + fg * 8];
                bfr[i] = *(const bf16x8*)&Bs0[(wc * 64 + i * 16 + fr) * 32 + fg * 8];
            }
            #pragma unroll
            for (int i = 0; i < 4; ++i)
                #pragma unroll
                for (int j = 0; j < 4; ++j)
                    acc[i][j] = __builtin_amdgcn_mfma_f32_16x16x32_bf16(
                        af[i], bfr[j], acc[i][j], 0, 0, 0);
        }
        {   // half 1
            bf16x8 af[4], bfr[4];
            #pragma unroll
            for (int i = 0; i < 4; ++i) {
                af[i]  = *(const bf16x8*)&As1[(wr * 64 + i * 16 + fr) * 32 + fg * 8];
                bfr[i] = *(const bf16x8*)&Bs1[(wc * 64 + i * 16 + fr) * 32 + fg * 8];
            }
            #pragma unroll
            for (int i = 0; i < 4; ++i)
                #pragma unroll
                for (int j = 0; j < 4; ++j)
                    acc[i][j] = __builtin_amdgcn_mfma_f32_16x16x32_bf16(
                        af[i], bfr[j], acc[i][j], 0, 0, 0);
        }
    }

    #pragma unroll
    for (int i = 0; i < 4; ++i) {
        #pragma unroll
        for (int j = 0; j < 4; ++j) {
            #pragma unroll
            for (int r = 0; r < 4; ++r) {
                int row = m0 + wr * 64 + i * 16 + fg * 4 + r;
                int col = n0 + wc * 64 + j * 16 + fr;
                float v = acc[i][j][r];
                if (BIAS)  v += bias[col];
                if (BIASR) v += bias[row];
                if (GELU) v = 0.5f * v * (1.f + erff(v * 0.70710678118f));
                size_t o = cbase + (size_t)row * ldc + col;
                if (PEADD) v += addp[(size_t)(row & 1023) * 512 + col];
                if (ADD)   v += addp[o];
                if (WF32) C32[o] = v;
                if (WBF16) C16[o] = f2b(v);
            }
        }
    }
}

// ---------------------------------------------------------------------------
// Complex per-mode channel mix. Inputs: ftt partials [z=ks*32+b][mc=128][c=512]
// (4 K-slices summed here) and transposed bf16 weights WT [h][m][e*64+o].
// Output acat bf16 [B*H*64o][128] (Re | Im). grid 512 = (h,m), block 256.
// ---------------------------------------------------------------------------
__global__ void k_modemix(const float* __restrict__ ftT,
                          const u16* __restrict__ wtre, const u16* __restrict__ wtim,
                          u16* __restrict__ acat) {
    __shared__ float wr_s[64][64];   // [e][o]
    __shared__ float wi_s[64][64];
    __shared__ float fr_s[32][64];   // [b][e]
    __shared__ float fi_s[32][64];
    int h = blockIdx.x >> 6, m = blockIdx.x & 63;
    int tid = threadIdx.x;
    const u16* wr_p = wtre + ((size_t)(h * 64 + m)) * 4096;
    const u16* wi_p = wtim + ((size_t)(h * 64 + m)) * 4096;
    for (int i = tid; i < 4096; i += 256) {      // contiguous 8 KB each
        wr_s[i >> 6][i & 63] = b2f(wr_p[i]);
        wi_s[i >> 6][i & 63] = b2f(wi_p[i]);
    }
    const size_t KS = (size_t)32 * 65536;
    for (int i = tid; i < 2048; i += 256) {      // lane-contiguous in e
        int b = i >> 6, e = i & 63;
        size_t f0 = (size_t)b * 65536 + (size_t)m * 512 + h * 64 + e;
        size_t f1 = f0 + (size_t)64 * 512;
        fr_s[b][e] = ftT[f0] + ftT[f0 + KS] + ftT[f0 + 2 * KS] + ftT[f0 + 3 * KS];
        fi_s[b][e] = ftT[f1] + ftT[f1 + KS] + ftT[f1 + 2 * KS] + ftT[f1 + 3 * KS];
    }
    __syncthreads();
    int o = tid & 63, bg = tid >> 6;
    for (int bb = bg; bb < 32; bb += 4) {
        float accr = 0.f, acci = 0.f;
        #pragma unroll 8
        for (int e = 0; e < 64; ++e) {
            float wr = wr_s[e][o], wi = wi_s[e][o];
            float fr = fr_s[bb][e], fi = fi_s[bb][e];
            accr += fr * wr - fi * wi;
            acci += fr * wi + fi * wr;
        }
        size_t base = (((size_t)(bb * 8 + h)) * 64 + o) * 128;
        acat[base + m]      = f2b(accr);
        acat[base + 64 + m] = f2b(acci);
    }
}

// ---------------------------------------------------------------------------
// moving-average decomp residual, rolling-window float2 form.
// grid (32 b, 16 lseg), block 256.
// ---------------------------------------------------------------------------
__global__ void k_madiff(const float* __restrict__ in, float* __restrict__ out,
                         u16* __restrict__ out16) {
    int b = blockIdx.x, ls = blockIdx.y;
    int d2 = threadIdx.x;                 // float2 column index, 0..255
    const float2* base = (const float2*)(in + (size_t)b * 524288) + d2;
    int l0 = ls * 64;
    float sx = 0.f, sy = 0.f;
    #pragma unroll
    for (int k = -12; k <= 12; ++k) {
        int ll = l0 + k;
        ll = ll < 0 ? 0 : (ll > 1023 ? 1023 : ll);
        float2 v = base[(size_t)ll * 256];
        sx += v.x; sy += v.y;
    }
    for (int li = 0; li < 64; ++li) {
        int l = l0 + li;
        float2 x = base[(size_t)l * 256];
        float vx = x.x - sx * (1.f / 25.f);
        float vy = x.y - sy * (1.f / 25.f);
        size_t o = (size_t)b * 262144 + (size_t)l * 256 + d2;   // float2 index
        ((float2*)out)[o] = float2{vx, vy};
        unsigned pk = (unsigned)f2b(vx) | ((unsigned)f2b(vy) << 16);
        ((unsigned*)out16)[o] = pk;
        int lp = l + 13; lp = lp > 1023 ? 1023 : lp;
        int lm = l - 12; lm = lm < 0 ? 0 : lm;
        float2 a = base[(size_t)lp * 256];
        float2 s = base[(size_t)lm * 256];
        sx += a.x - s.x; sy += a.y - s.y;
    }
}

// ---------------------------------------------------------------------------
// LayerNorm over last dim (512)
// ---------------------------------------------------------------------------
__global__ void k_layernorm(const float* __restrict__ in, const float* __restrict__ g,
                            const float* __restrict__ bta, float* __restrict__ out) {
    int row = blockIdx.x;
    int tid = threadIdx.x;
    const float* r = in + (size_t)row * 512;
    float v0 = r[tid], v1 = r[tid + 256];
    float s = v0 + v1, s2 = v0 * v0 + v1 * v1;
    #pragma unroll
    for (int off = 32; off; off >>= 1) {
        s  += __shfl_down(s, off);
        s2 += __shfl_down(s2, off);
    }
    __shared__ float ws[4], ws2[4];
    if ((tid & 63) == 0) { ws[tid >> 6] = s; ws2[tid >> 6] = s2; }
    __syncthreads();
    if (tid == 0) {
        ws[0]  = ws[0] + ws[1] + ws[2] + ws[3];
        ws2[0] = ws2[0] + ws2[1] + ws2[2] + ws2[3];
    }
    __syncthreads();
    float mu = ws[0] * (1.f / 512.f);
    float var = ws2[0] * (1.f / 512.f) - mu * mu;
    float rs = rsqrtf(var + 1e-5f);
    float* o = out + (size_t)row * 512;
    o[tid]       = (v0 - mu) * rs * g[tid]       + bta[tid];
    o[tid + 256] = (v1 - mu) * rs * g[tid + 256] + bta[tid + 256];
}

// Fused head LN + regression partial
__global__ void k_lnreg(const float* __restrict__ in, const float* __restrict__ g,
                        const float* __restrict__ bta, const float* __restrict__ rw,
                        float* __restrict__ partial) {
    int row = blockIdx.x;                 // b*1024 + l
    int tid = threadIdx.x;
    const float* r = in + (size_t)row * 512;
    float v0 = r[tid], v1 = r[tid + 256];
    float s = v0 + v1, s2 = v0 * v0 + v1 * v1;
    #pragma unroll
    for (int off = 32; off; off >>= 1) {
        s  += __shfl_down(s, off);
        s2 += __shfl_down(s2, off);
    }
    __shared__ float ws[4], ws2[4];
    if ((tid & 63) == 0) { ws[tid >> 6] = s; ws2[tid >> 6] = s2; }
    __syncthreads();
    if (tid == 0) {
        ws[0]  = ws[0] + ws[1] + ws[2] + ws[3];
        ws2[0] = ws2[0] + ws2[1] + ws2[2] + ws2[3];
    }
    __syncthreads();
    float mu = ws[0] * (1.f / 512.f);
    float var = ws2[0] * (1.f / 512.f) - mu * mu;
    float rs = rsqrtf(var + 1e-5f);
    const float* wrow = rw + (size_t)(row & 1023) * 512;
    float y0 = (v0 - mu) * rs * g[tid]       + bta[tid];
    float y1 = (v1 - mu) * rs * g[tid + 256] + bta[tid + 256];
    float p = y0 * wrow[tid] + y1 * wrow[tid + 256];
    #pragma unroll
    for (int off = 32; off; off >>= 1) p += __shfl_down(p, off);
    __shared__ float wp[4];
    if ((tid & 63) == 0) wp[tid >> 6] = p;
    __syncthreads();
    if (tid == 0) partial[row] = wp[0] + wp[1] + wp[2] + wp[3];
}

// out[b] = sum_l partial[b*1024+l] + reg_b (deterministic fixed-order tree)
__global__ void k_regf2(const float* __restrict__ partial, const float* __restrict__ rb,
                        float* __restrict__ out) {
    int b = blockIdx.x;
    int tid = threadIdx.x;
    const float* p = partial + (size_t)b * 1024;
    float s = p[tid] + p[tid + 256] + p[tid + 512] + p[tid + 768];
    #pragma unroll
    for (int off = 32; off; off >>= 1) s += __shfl_down(s, off);
    __shared__ float ws[4];
    if ((tid & 63) == 0) ws[tid >> 6] = s;
    __syncthreads();
    if (tid == 0) out[b] = ws[0] + ws[1] + ws[2] + ws[3] + rb[0];
}

// column-mean phase 1: partial[b][seg][d] = sum over 128 l's
__global__ __launch_bounds__(512) void k_colmean1(const float* __restrict__ in,
                                                  float* __restrict__ part) {
    int b = blockIdx.x, seg = blockIdx.y;   // 32 x 8
    int d = threadIdx.x;                    // 512
    const float* p = in + ((size_t)b * 1024 + seg * 128) * 512 + d;
    float s = 0.f;
    for (int l = 0; l < 128; ++l) s += p[(size_t)l * 512];
    part[((size_t)b * 8 + seg) * 512 + d] = s;
}

// column-mean phase 2: mean[b][d] = (sum over 8 segs) / 1024
__global__ void k_colmean2(const float* __restrict__ part, float* __restrict__ mean) {
    int i = blockIdx.x * 256 + threadIdx.x;   // 16384
    int b = i >> 9, d = i & 511;
    float s = 0.f;
    #pragma unroll
    for (int seg = 0; seg < 8; ++seg) s += part[((size_t)b * 8 + seg) * 512 + d];
    mean[i] = s * (1.f / 1024.f);
}

// subtract per-(b,d) mean, write fp32 in place + bf16 mirror
__global__ void k_subcol(float* __restrict__ x, const float* __restrict__ mean,
                         u16* __restrict__ x16) {
    int idx = blockIdx.x * 256 + threadIdx.x;
    int d = idx & 511;
    int b = idx >> 19;
    float v = x[idx] - mean[b * 512 + d];
    x[idx] = v;
    x16[idx] = f2b(v);
}

// ---------------------------------------------------------------------------
extern "C" void kernel_launch(void* const* d_in, const int* in_sizes, int n_in,
                              void* d_out, int out_size, void* d_ws, size_t ws_size,
                              hipStream_t stream) {
    const float* x_enc  = (const float*)d_in[0];
    const float* conv_w = (const float*)d_in[1];
    const float* wq     = (const float*)d_in[2];
    const float* bq     = (const float*)d_in[3];
    const float* wo     = (const float*)d_in[4];
    const float* bo     = (const float*)d_in[5];
    const float* fw_re  = (const float*)d_in[6];
    const float* fw_im  = (const float*)d_in[7];
    const float* c1w    = (const float*)d_in[8];
    const float* c2w    = (const float*)d_in[9];
    const float* enc_g  = (const float*)d_in[10];
    const float* enc_b  = (const float*)d_in[11];
    const float* ff_w   = (const float*)d_in[12];
    const float* ff_b   = (const float*)d_in[13];
    const float* ffn_g  = (const float*)d_in[14];
    const float* ffn_b  = (const float*)d_in[15];
    const float* reg_w  = (const float*)d_in[16];
    const float* reg_b  = (const float*)d_in[17];
    float* out = (float*)d_out;

    // ---- workspace layout (byte offsets; total 227,606,528 B ≈ 227.6 MB) ----
    char* wsb = (char*)d_ws;
    float* F0    = (float*)(wsb);                        // 64 MiB fp32 [B,L,D]
    float* F1    = (float*)(wsb + 67108864);             // 64 MiB fp32 / y16 / ftt partials
    u16*   A16   = (u16*)  (wsb + 134217728);            // 32 MiB bf16 [B,L,D] (x mirror)
    u16*   U16   = (u16*)  (wsb + 167772160);            // 32 MiB bf16 (im2col A2 / qT / new_x)
    u16*   AC16  = (u16*)  (wsb + 201326592);            // 4 MiB  bf16 (W2 at setup / acat)
    float* FTT   = (float*)(wsb + 205520896);            // 8 MiB: WT16 re+im during layers; head partials after
    float* PE    = (float*)(wsb + 213909504);            // 2 MiB  fp32 [1024][512]
    u16*   TRIG  = (u16*)  (wsb + 216006656);            // 256 KiB [128][1024]
    u16*   TCAT  = (u16*)  (wsb + 216268800);            // 256 KiB [1024][128]
    u16*   WQ16  = (u16*)  (wsb + 216530944);            // 1 MiB [2][512][512]
    u16*   WO16  = (u16*)  (wsb + 217579520);            // 1 MiB
    u16*   C1W16 = (u16*)  (wsb + 218628096);            // 4 MiB [2][2048][512]
    u16*   C2W16 = (u16*)  (wsb + 222822400);            // 4 MiB [2][512][2048]
    u16*   FFW16 = (u16*)  (wsb + 227016704);            // 512 KiB
    float* CMEAN = (float*)(wsb + 227540992);            // 64 KiB
    const size_t need_bytes = 227606528;
    if (ws_size < need_bytes) return;   // clean diagnostic failure

    u16* WTRE16 = (u16*)FTT;             // 4 MiB [8][64][4096] bf16 (per-layer)
    u16* WTIM16 = WTRE16 + 2097152;      // 4 MiB

    const int BLD = B_ * L_ * D_;
    dim3 blk(256);

    // tables + weight casts
    k_tables<<<2048, blk, 0, stream>>>(TRIG, TCAT, PE);
    k_cast<<<512,  blk, 0, stream>>>(wq,   WQ16,  524288 / 4);
    k_cast<<<512,  blk, 0, stream>>>(wo,   WO16,  524288 / 4);
    k_cast<<<2048, blk, 0, stream>>>(c1w,  C1W16, 2097152 / 4);
    k_cast<<<2048, blk, 0, stream>>>(c2w,  C2W16, 2097152 / 4);
    k_cast<<<256,  blk, 0, stream>>>(ff_w, FFW16, 262144 / 4);
    // embedding as im2col GEMM: A2 in U16, W2 in AC16, PE added in epilogue
    k_wpad<<<128, blk, 0, stream>>>(conv_w, AC16);
    k_im2col<<<2048, blk, 0, stream>>>(x_enc, U16);
    k_mfma<false, false, false, false, true, true, false, true>
        <<<dim3(4, 256), blk, 0, stream>>>(
        U16, AC16, nullptr, PE, F0, A16, 64, 64, 64, 512, 0, 0);

    float* cur = F0;
    float* alt = F1;
    const dim3 g_big(4, 256);     // M=32768, N=512

    for (int l = 0; l < 2; ++l) {
        const float* bq_l = bq + l * 512;
        const float* bo_l = bo + l * 512;
        const u16* wo16_l = WO16 + (size_t)l * 262144;
        const u16* c1_l   = C1W16 + (size_t)l * DFF_ * D_;
        const u16* c2_l   = C2W16 + (size_t)l * D_ * DFF_;
        const float* fwre_l = fw_re + (size_t)l * H_ * E_ * E_ * M_;
        const float* fwim_l = fw_im + (size_t)l * H_ * E_ * E_ * M_;

        // transpose+cast fourier weights for this layer -> WT16 (coalesced)
        k_wtrans<<<dim3(64, 8, 2), blk, 0, stream>>>(fwre_l, fwim_l, WTRE16, WTIM16);
        // qT[c][b*1024+l] = wq @ x^T + bq  (swapped operands, direct bf16)
        k_mfma<false, true, false, false, false, true><<<dim3(256, 4), blk, 0, stream>>>(
            WQ16 + (size_t)l * 262144, A16, bq_l, nullptr, nullptr, U16,
            512, 512, 512, 32768, 0, 0);
        // forward DFT, transposed output + K-split x4:
        // partials [z=ks*32+b][128 mc][512 c] -> alt (dead until madiff)
        float* ftt4 = alt;
        k_mfma<false, false, false, false, true, false, true>
            <<<dim3(4, 1, 128), blk, 0, stream>>>(
            TRIG, U16, nullptr, nullptr, ftt4, nullptr,
            256, 1024, 32768, 512, 0, 0);
        // complex mode mixing (sums 4 K-slice partials; coalesced reads) -> AC16
        k_modemix<<<512, blk, 0, stream>>>(ftt4, WTRE16, WTIM16, AC16);
        // inverse DFT as GEMM -> U16 = new_x bf16 [B,H,E,L]
        k_mfma<false, false, false, false, false, true><<<dim3(8, 128), blk, 0, stream>>>(
            AC16, TCAT, nullptr, nullptr, nullptr, U16, 128, 128, 128, 1024, 0, 0);
        // x = x + (new_x @ wo^T + bo) -> cur (in-place add)
        k_mfma<true, false, false, true, true, false><<<g_big, blk, 0, stream>>>(
            U16, wo16_l, bo_l, cur, cur, nullptr, 512, 512, 512, 512, 0, 0);
        // x = x - ma(x) -> alt fp32 + A16 bf16 ; swap
        k_madiff<<<dim3(32, 16), blk, 0, stream>>>(cur, alt, A16);
        { float* t = cur; cur = alt; alt = t; }
        // FFN: 2 serial M-chunks of 16384 rows, full DFF per chunk.
        u16* y16 = (u16*)alt;
        for (int c = 0; c < 2; ++c) {
            const size_t aoff = (size_t)c * 16384 * 512;
            k_mfma<false, false, true, false, false, true><<<dim3(16, 128), blk, 0, stream>>>(
                A16 + aoff, c1_l, nullptr, nullptr, nullptr, y16,
                512, 512, 512, 2048, 0, 0);
            k_mfma<false, false, false, true, true, false><<<dim3(4, 128), blk, 0, stream>>>(
                y16, c2_l, nullptr, cur + aoff, cur + aoff, nullptr,
                2048, 2048, 2048, 512, 0, 0);
        }
        // x = xy - ma(xy) -> alt + A16 ; swap
        k_madiff<<<dim3(32, 16), blk, 0, stream>>>(cur, alt, A16);
        { float* t = cur; cur = alt; alt = t; }
    }

    // my_Layernorm: LN then subtract per-(b,d) mean over L
    k_layernorm<<<32768, blk, 0, stream>>>(cur, enc_g, enc_b, alt);
    k_colmean1<<<dim3(B_, 8), 512, 0, stream>>>(alt, FTT);
    k_colmean2<<<64, blk, 0, stream>>>(FTT, CMEAN);
    k_subcol<<<BLD / 256, blk, 0, stream>>>(alt, CMEAN, A16);
    // head Linear -> cur, then fused LN+regression
    k_mfma<true, false, false, false, true, false><<<g_big, blk, 0, stream>>>(
        A16, FFW16, ff_b, nullptr, cur, nullptr, 512, 512, 512, 512, 0, 0);
    k_lnreg<<<32768, blk, 0, stream>>>(cur, ffn_g, ffn_b, reg_w, FTT);
    k_regf2<<<32, blk, 0, stream>>>(FTT, reg_b, out);
}

// Round 16
// 1050.254 us; speedup vs baseline: 1.1860x; 1.0435x over previous
//
#include <hip/hip_runtime.h>
#include <math.h>

static constexpr int B_   = 32;
static constexpr int L_   = 1024;
static constexpr int CIN_ = 21;
static constexpr int D_   = 512;
static constexpr int H_   = 8;
static constexpr int E_   = 64;
static constexpr int DFF_ = 2048;
static constexpr int M_   = 64;   // MODES

typedef unsigned short u16;
typedef __attribute__((ext_vector_type(8))) short bf16x8;
typedef __attribute__((ext_vector_type(4))) float f32x4;
typedef __attribute__((ext_vector_type(4))) unsigned short u16x4;

// RNE float->bf16 (bit-level, no header dependency)
static __device__ __forceinline__ u16 f2b(float f) {
    unsigned u = __float_as_uint(f);
    unsigned r = (u + 0x7fffu + ((u >> 16) & 1u)) >> 16;
    return (u16)r;
}
static __device__ __forceinline__ float b2f(u16 x) {
    return __uint_as_float((unsigned)x << 16);
}

// async global->LDS 16B/lane copy (CK-style int-roundtrip AS casts;
// LDS dest is wave-uniform, lanes land at base + lane*16)
static __device__ __forceinline__ void gload16(const u16* g, u16* l) {
    unsigned long long ga = (unsigned long long)g;
    unsigned la = (unsigned)(unsigned long long)l;   // low 32 bits = LDS offset
    __builtin_amdgcn_global_load_lds(
        (const __attribute__((address_space(1))) void*)ga,
        (__attribute__((address_space(3))) void*)(unsigned long long)la,
        16, 0, 0);
}

// ---------------------------------------------------------------------------
// Tables (fp32 trig): TRIG16 [128 mcat][1024 l] (rows 0-63 cos, 64-127 -sin);
// TCAT16 [1024][128] inverse-DFT coefficients (1/1024 baked in);
// PE fp32 [1024][512].
// ---------------------------------------------------------------------------
__global__ void k_tables(u16* trig, u16* tcat, float* pe) {
    int idx = blockIdx.x * 256 + threadIdx.x;   // 0 .. 524287
    if (idx < 131072) {                          // trig [mc][l]
        int l = idx & 1023, mc = idx >> 10;
        int m = mc & 63;
        float th = (float)((m * l) & 1023) * 0.006135923151542565f; // 2pi/1024
        float v = (mc < 64) ? cosf(th) : (-sinf(th));
        trig[idx] = f2b(v);
    }
    if (idx < 131072) {                          // tcat [l][k]
        int k = idx & 127, l = idx >> 7;
        int m = k & 63;
        float th = (float)((m * l) & 1023) * 0.006135923151542565f;
        float v;
        if (k < 64) v = (m == 0) ? 1.0f : (2.0f * cosf(th));
        else        v = (m == 0) ? 0.0f : (-2.0f * sinf(th));
        tcat[idx] = f2b(v * (1.0f / 1024.0f));
    }
    if (idx < 524288) {                          // pe [l][d]
        int d = idx & 511, l = idx >> 9;
        int i2 = d >> 1;
        float div = expf(-(float)(2 * i2) * 0.017988946039015984f);
        float arg = (float)l * div;
        pe[idx] = (d & 1) ? cosf(arg) : sinf(arg);
    }
}

// generic fp32 -> bf16 cast (n multiple of 4)
__global__ void k_cast(const float* __restrict__ in, u16* __restrict__ out, int n4) {
    int i = blockIdx.x * 256 + threadIdx.x;
    if (i < n4) {
        float4 v = ((const float4*)in)[i];
        u16x4 o = { f2b(v.x), f2b(v.y), f2b(v.z), f2b(v.w) };
        ((u16x4*)out)[i] = o;
    }
}

// ---------------------------------------------------------------------------
// Fourier-weight transpose: [h][e][o][m] fp32 -> [h][m][e*64+o] bf16.
// ---------------------------------------------------------------------------
__global__ void k_wtrans(const float* __restrict__ re, const float* __restrict__ im,
                         u16* __restrict__ outre, u16* __restrict__ outim) {
    __shared__ float t[64][65];
    const float* src = blockIdx.z ? im : re;
    u16* dst = blockIdx.z ? outim : outre;
    int h = blockIdx.y, eo0 = blockIdx.x * 64;
    int j = threadIdx.x & 63, i0 = threadIdx.x >> 6;
    for (int i = i0; i < 64; i += 4)
        t[i][j] = src[(size_t)h * 262144 + (size_t)(eo0 + i) * 64 + j];
    __syncthreads();
    for (int i = i0; i < 64; i += 4)
        dst[(size_t)h * 262144 + (size_t)i * 4096 + eo0 + j] = f2b(t[j][i]);
}

// ---------------------------------------------------------------------------
// im2col for embedding conv: A2[b*1024+l][kc] = xe[b][(l + kc%3 - 1) mod L][kc/3]
// (kc < 63; col 63 zero-padded). bf16 output, coalesced u16x4 writes.
// ---------------------------------------------------------------------------
__global__ void k_im2col(const float* __restrict__ xe, u16* __restrict__ a2) {
    int idx = blockIdx.x * 256 + threadIdx.x;    // 0 .. 524287 (32768*16)
    int row = idx >> 4, g = idx & 15;
    int b = row >> 10, l = row & 1023;
    u16x4 o;
    #pragma unroll
    for (int j = 0; j < 4; ++j) {
        int kc = g * 4 + j;
        float v = 0.f;
        if (kc < 63) {
            int c = kc / 3, k = kc - c * 3;
            int ls = (l + k - 1 + 1024) & 1023;
            v = xe[((size_t)b * 1024 + ls) * 21 + c];
        }
        o[j] = f2b(v);
    }
    *(u16x4*)(a2 + (size_t)row * 64 + g * 4) = o;
}

// conv weight pad+cast: w2[d][kc] = cw[d*63+kc] (kc<63), 0 at kc=63
__global__ void k_wpad(const float* __restrict__ cw, u16* __restrict__ w2) {
    int idx = blockIdx.x * 256 + threadIdx.x;   // 0..32767
    int d = idx >> 6, kc = idx & 63;
    float v = (kc < 63) ? cw[(size_t)d * 63 + kc] : 0.f;
    w2[idx] = f2b(v);
}

// ---------------------------------------------------------------------------
// bf16 MFMA NT GEMM: 128x128 tile, 4 waves, 16x16x32 MFMA, BK=64 split-
// buffered (64B row pitch), global_load_lds staging, 3 blocks/CU.
// Chunked-XCD block swizzle (T1): consecutive logical tiles share the A-panel;
// mapping keeps each XCD's blocks on a contiguous logical range so shared
// A-rows are L2-local (grid size must be a multiple of 8 — all ours are).
// BIAS per-col, BIASR per-row. DFTZ: transposed-output DFT (z-indexed, no
// swizzle). PEADD: epilogue adds addp[(row&1023)*512+col].
// ---------------------------------------------------------------------------
template<bool BIAS, bool BIASR, bool GELU, bool ADD, bool WF32, bool WBF16,
         bool DFTZ = false, bool PEADD = false>
__global__ __launch_bounds__(256, 3) void k_mfma(
        const u16* __restrict__ A, const u16* __restrict__ W,
        const float* __restrict__ bias, const float* addp,
        float* C32, u16* C16,
        int K, int lda, int ldw, int ldc, long strideA, long strideC) {
    __shared__ __align__(16) u16 As0[128 * 32];
    __shared__ __align__(16) u16 As1[128 * 32];
    __shared__ __align__(16) u16 Bs0[128 * 32];
    __shared__ __align__(16) u16 Bs1[128 * 32];
    const int tid  = threadIdx.x;
    const int lane = tid & 63, wid = tid >> 6;
    int m0, n0;
    size_t cbase;
    if constexpr (DFTZ) {
        int z  = blockIdx.z;
        int ks = z >> 5;                     // K-slice 0..3
        m0 = 0;
        n0 = blockIdx.x * 128;
        A += (size_t)ks * 256;
        W += (size_t)(z & 31) * 1024 + (size_t)ks * 256;
        cbase = (size_t)z * 65536;
    } else {
        // T1 chunked-XCD swizzle: physical lid -> logical tile id such that
        // each XCD (lid mod 8) owns a contiguous logical range.
        int gx = gridDim.x;
        int nwg = gx * gridDim.y;
        int lid = blockIdx.y * gx + blockIdx.x;
        int logical = (lid & 7) * (nwg >> 3) + (lid >> 3);
        m0 = (logical / gx) * 128;
        n0 = (logical % gx) * 128;
        A += (size_t)blockIdx.z * strideA;
        cbase = (size_t)blockIdx.z * strideC;
    }

    // staging: wave wid owns rows [32*wid, 32*wid+32); lane -> (row l>>2, col 8*(l&3))
    const int srow = lane >> 2, scol = (lane & 3) * 8;
    const u16* ga0 = A + (size_t)(m0 + wid * 32 + srow) * lda + scol;
    const u16* ga1 = ga0 + (size_t)16 * lda;
    const u16* gb0 = W + (size_t)(n0 + wid * 32 + srow) * ldw + scol;
    const u16* gb1 = gb0 + (size_t)16 * ldw;
    const int lofs0 = wid * 32 * 32, lofs1 = lofs0 + 16 * 32;

    const int wr = wid >> 1, wc = wid & 1;
    const int fr = lane & 15, fg = lane >> 4;

    f32x4 acc[4][4];
    #pragma unroll
    for (int i = 0; i < 4; ++i)
        #pragma unroll
        for (int j = 0; j < 4; ++j)
            acc[i][j] = f32x4{0.f, 0.f, 0.f, 0.f};

    for (int k0 = 0; k0 < K; k0 += 64) {
        __syncthreads();                    // prev iter's ds_reads done
        gload16(ga0 + k0,      &As0[lofs0]);
        gload16(ga1 + k0,      &As0[lofs1]);
        gload16(gb0 + k0,      &Bs0[lofs0]);
        gload16(gb1 + k0,      &Bs0[lofs1]);
        gload16(ga0 + k0 + 32, &As1[lofs0]);
        gload16(ga1 + k0 + 32, &As1[lofs1]);
        gload16(gb0 + k0 + 32, &Bs1[lofs0]);
        gload16(gb1 + k0 + 32, &Bs1[lofs1]);
        __syncthreads();                    // vmcnt(0) drained -> both halves ready
        {   // half 0
            bf16x8 af[4], bfr[4];
            #pragma unroll
            for (int i = 0; i < 4; ++i) {
                af[i]  = *(const bf16x8*)&As0[(wr * 64 + i * 16 + fr) * 32 + fg * 8];
                bfr[i] = *(const bf16x8*)&Bs0[(wc * 64 + i * 16 + fr) * 32 + fg * 8];
            }
            #pragma unroll
            for (int i = 0; i < 4; ++i)
                #pragma unroll
                for (int j = 0; j < 4; ++j)
                    acc[i][j] = __builtin_amdgcn_mfma_f32_16x16x32_bf16(
                        af[i], bfr[j], acc[i][j], 0, 0, 0);
        }
        {   // half 1
            bf16x8 af[4], bfr[4];
            #pragma unroll
            for (int i = 0; i < 4; ++i) {
                af[i]  = *(const bf16x8*)&As1[(wr * 64 + i * 16 + fr) * 32 + fg * 8];
                bfr[i] = *(const bf16x8*)&Bs1[(wc * 64 + i * 16 + fr) * 32 + fg * 8];
            }
            #pragma unroll
            for (int i = 0; i < 4; ++i)
                #pragma unroll
                for (int j = 0; j < 4; ++j)
                    acc[i][j] = __builtin_amdgcn_mfma_f32_16x16x32_bf16(
                        af[i], bfr[j], acc[i][j], 0, 0, 0);
        }
    }

    #pragma unroll
    for (int i = 0; i < 4; ++i) {
        #pragma unroll
        for (int j = 0; j < 4; ++j) {
            #pragma unroll
            for (int r = 0; r < 4; ++r) {
                int row = m0 + wr * 64 + i * 16 + fg * 4 + r;
                int col = n0 + wc * 64 + j * 16 + fr;
                float v = acc[i][j][r];
                if (BIAS)  v += bias[col];
                if (BIASR) v += bias[row];
                if (GELU) v = 0.5f * v * (1.f + erff(v * 0.70710678118f));
                size_t o = cbase + (size_t)row * ldc + col;
                if (PEADD) v += addp[(size_t)(row & 1023) * 512 + col];
                if (ADD)   v += addp[o];
                if (WF32) C32[o] = v;
                if (WBF16) C16[o] = f2b(v);
            }
        }
    }
}

// ---------------------------------------------------------------------------
// Complex per-mode channel mix. Inputs: ftt partials [z=ks*32+b][mc=128][c=512]
// (4 K-slices summed here) and transposed bf16 weights WT [h][m][e*64+o].
// Output acat bf16 [B*H*64o][128] (Re | Im). grid 512 = (h,m), block 256.
// ---------------------------------------------------------------------------
__global__ void k_modemix(const float* __restrict__ ftT,
                          const u16* __restrict__ wtre, const u16* __restrict__ wtim,
                          u16* __restrict__ acat) {
    __shared__ float wr_s[64][64];   // [e][o]
    __shared__ float wi_s[64][64];
    __shared__ float fr_s[32][64];   // [b][e]
    __shared__ float fi_s[32][64];
    int h = blockIdx.x >> 6, m = blockIdx.x & 63;
    int tid = threadIdx.x;
    const u16* wr_p = wtre + ((size_t)(h * 64 + m)) * 4096;
    const u16* wi_p = wtim + ((size_t)(h * 64 + m)) * 4096;
    for (int i = tid; i < 4096; i += 256) {      // contiguous 8 KB each
        wr_s[i >> 6][i & 63] = b2f(wr_p[i]);
        wi_s[i >> 6][i & 63] = b2f(wi_p[i]);
    }
    const size_t KS = (size_t)32 * 65536;
    for (int i = tid; i < 2048; i += 256) {      // lane-contiguous in e
        int b = i >> 6, e = i & 63;
        size_t f0 = (size_t)b * 65536 + (size_t)m * 512 + h * 64 + e;
        size_t f1 = f0 + (size_t)64 * 512;
        fr_s[b][e] = ftT[f0] + ftT[f0 + KS] + ftT[f0 + 2 * KS] + ftT[f0 + 3 * KS];
        fi_s[b][e] = ftT[f1] + ftT[f1 + KS] + ftT[f1 + 2 * KS] + ftT[f1 + 3 * KS];
    }
    __syncthreads();
    int o = tid & 63, bg = tid >> 6;
    for (int bb = bg; bb < 32; bb += 4) {
        float accr = 0.f, acci = 0.f;
        #pragma unroll 8
        for (int e = 0; e < 64; ++e) {
            float wr = wr_s[e][o], wi = wi_s[e][o];
            float fr = fr_s[bb][e], fi = fi_s[bb][e];
            accr += fr * wr - fi * wi;
            acci += fr * wi + fi * wr;
        }
        size_t base = (((size_t)(bb * 8 + h)) * 64 + o) * 128;
        acat[base + m]      = f2b(accr);
        acat[base + 64 + m] = f2b(acci);
    }
}

// ---------------------------------------------------------------------------
// moving-average decomp residual, rolling-window float2 form.
// grid (32 b, 16 lseg), block 256.
// ---------------------------------------------------------------------------
__global__ void k_madiff(const float* __restrict__ in, float* __restrict__ out,
                         u16* __restrict__ out16) {
    int b = blockIdx.x, ls = blockIdx.y;
    int d2 = threadIdx.x;                 // float2 column index, 0..255
    const float2* base = (const float2*)(in + (size_t)b * 524288) + d2;
    int l0 = ls * 64;
    float sx = 0.f, sy = 0.f;
    #pragma unroll
    for (int k = -12; k <= 12; ++k) {
        int ll = l0 + k;
        ll = ll < 0 ? 0 : (ll > 1023 ? 1023 : ll);
        float2 v = base[(size_t)ll * 256];
        sx += v.x; sy += v.y;
    }
    for (int li = 0; li < 64; ++li) {
        int l = l0 + li;
        float2 x = base[(size_t)l * 256];
        float vx = x.x - sx * (1.f / 25.f);
        float vy = x.y - sy * (1.f / 25.f);
        size_t o = (size_t)b * 262144 + (size_t)l * 256 + d2;   // float2 index
        ((float2*)out)[o] = float2{vx, vy};
        unsigned pk = (unsigned)f2b(vx) | ((unsigned)f2b(vy) << 16);
        ((unsigned*)out16)[o] = pk;
        int lp = l + 13; lp = lp > 1023 ? 1023 : lp;
        int lm = l - 12; lm = lm < 0 ? 0 : lm;
        float2 a = base[(size_t)lp * 256];
        float2 s = base[(size_t)lm * 256];
        sx += a.x - s.x; sy += a.y - s.y;
    }
}

// ---------------------------------------------------------------------------
// LayerNorm over last dim (512)
// ---------------------------------------------------------------------------
__global__ void k_layernorm(const float* __restrict__ in, const float* __restrict__ g,
                            const float* __restrict__ bta, float* __restrict__ out) {
    int row = blockIdx.x;
    int tid = threadIdx.x;
    const float* r = in + (size_t)row * 512;
    float v0 = r[tid], v1 = r[tid + 256];
    float s = v0 + v1, s2 = v0 * v0 + v1 * v1;
    #pragma unroll
    for (int off = 32; off; off >>= 1) {
        s  += __shfl_down(s, off);
        s2 += __shfl_down(s2, off);
    }
    __shared__ float ws[4], ws2[4];
    if ((tid & 63) == 0) { ws[tid >> 6] = s; ws2[tid >> 6] = s2; }
    __syncthreads();
    if (tid == 0) {
        ws[0]  = ws[0] + ws[1] + ws[2] + ws[3];
        ws2[0] = ws2[0] + ws2[1] + ws2[2] + ws2[3];
    }
    __syncthreads();
    float mu = ws[0] * (1.f / 512.f);
    float var = ws2[0] * (1.f / 512.f) - mu * mu;
    float rs = rsqrtf(var + 1e-5f);
    float* o = out + (size_t)row * 512;
    o[tid]       = (v0 - mu) * rs * g[tid]       + bta[tid];
    o[tid + 256] = (v1 - mu) * rs * g[tid + 256] + bta[tid + 256];
}

// Fused head LN + regression partial
__global__ void k_lnreg(const float* __restrict__ in, const float* __restrict__ g,
                        const float* __restrict__ bta, const float* __restrict__ rw,
                        float* __restrict__ partial) {
    int row = blockIdx.x;                 // b*1024 + l
    int tid = threadIdx.x;
    const float* r = in + (size_t)row * 512;
    float v0 = r[tid], v1 = r[tid + 256];
    float s = v0 + v1, s2 = v0 * v0 + v1 * v1;
    #pragma unroll
    for (int off = 32; off; off >>= 1) {
        s  += __shfl_down(s, off);
        s2 += __shfl_down(s2, off);
    }
    __shared__ float ws[4], ws2[4];
    if ((tid & 63) == 0) { ws[tid >> 6] = s; ws2[tid >> 6] = s2; }
    __syncthreads();
    if (tid == 0) {
        ws[0]  = ws[0] + ws[1] + ws[2] + ws[3];
        ws2[0] = ws2[0] + ws2[1] + ws2[2] + ws2[3];
    }
    __syncthreads();
    float mu = ws[0] * (1.f / 512.f);
    float var = ws2[0] * (1.f / 512.f) - mu * mu;
    float rs = rsqrtf(var + 1e-5f);
    const float* wrow = rw + (size_t)(row & 1023) * 512;
    float y0 = (v0 - mu) * rs * g[tid]       + bta[tid];
    float y1 = (v1 - mu) * rs * g[tid + 256] + bta[tid + 256];
    float p = y0 * wrow[tid] + y1 * wrow[tid + 256];
    #pragma unroll
    for (int off = 32; off; off >>= 1) p += __shfl_down(p, off);
    __shared__ float wp[4];
    if ((tid & 63) == 0) wp[tid >> 6] = p;
    __syncthreads();
    if (tid == 0) partial[row] = wp[0] + wp[1] + wp[2] + wp[3];
}

// out[b] = sum_l partial[b*1024+l] + reg_b (deterministic fixed-order tree)
__global__ void k_regf2(const float* __restrict__ partial, const float* __restrict__ rb,
                        float* __restrict__ out) {
    int b = blockIdx.x;
    int tid = threadIdx.x;
    const float* p = partial + (size_t)b * 1024;
    float s = p[tid] + p[tid + 256] + p[tid + 512] + p[tid + 768];
    #pragma unroll
    for (int off = 32; off; off >>= 1) s += __shfl_down(s, off);
    __shared__ float ws[4];
    if ((tid & 63) == 0) ws[tid >> 6] = s;
    __syncthreads();
    if (tid == 0) out[b] = ws[0] + ws[1] + ws[2] + ws[3] + rb[0];
}

// column-mean phase 1: partial[b][seg][d] = sum over 128 l's
__global__ __launch_bounds__(512) void k_colmean1(const float* __restrict__ in,
                                                  float* __restrict__ part) {
    int b = blockIdx.x, seg = blockIdx.y;   // 32 x 8
    int d = threadIdx.x;                    // 512
    const float* p = in + ((size_t)b * 1024 + seg * 128) * 512 + d;
    float s = 0.f;
    for (int l = 0; l < 128; ++l) s += p[(size_t)l * 512];
    part[((size_t)b * 8 + seg) * 512 + d] = s;
}

// column-mean phase 2: mean[b][d] = (sum over 8 segs) / 1024
__global__ void k_colmean2(const float* __restrict__ part, float* __restrict__ mean) {
    int i = blockIdx.x * 256 + threadIdx.x;   // 16384
    int b = i >> 9, d = i & 511;
    float s = 0.f;
    #pragma unroll
    for (int seg = 0; seg < 8; ++seg) s += part[((size_t)b * 8 + seg) * 512 + d];
    mean[i] = s * (1.f / 1024.f);
}

// subtract per-(b,d) mean, write fp32 in place + bf16 mirror
__global__ void k_subcol(float* __restrict__ x, const float* __restrict__ mean,
                         u16* __restrict__ x16) {
    int idx = blockIdx.x * 256 + threadIdx.x;
    int d = idx & 511;
    int b = idx >> 19;
    float v = x[idx] - mean[b * 512 + d];
    x[idx] = v;
    x16[idx] = f2b(v);
}

// ---------------------------------------------------------------------------
extern "C" void kernel_launch(void* const* d_in, const int* in_sizes, int n_in,
                              void* d_out, int out_size, void* d_ws, size_t ws_size,
                              hipStream_t stream) {
    const float* x_enc  = (const float*)d_in[0];
    const float* conv_w = (const float*)d_in[1];
    const float* wq     = (const float*)d_in[2];
    const float* bq     = (const float*)d_in[3];
    const float* wo     = (const float*)d_in[4];
    const float* bo     = (const float*)d_in[5];
    const float* fw_re  = (const float*)d_in[6];
    const float* fw_im  = (const float*)d_in[7];
    const float* c1w    = (const float*)d_in[8];
    const float* c2w    = (const float*)d_in[9];
    const float* enc_g  = (const float*)d_in[10];
    const float* enc_b  = (const float*)d_in[11];
    const float* ff_w   = (const float*)d_in[12];
    const float* ff_b   = (const float*)d_in[13];
    const float* ffn_g  = (const float*)d_in[14];
    const float* ffn_b  = (const float*)d_in[15];
    const float* reg_w  = (const float*)d_in[16];
    const float* reg_b  = (const float*)d_in[17];
    float* out = (float*)d_out;

    // ---- workspace layout (byte offsets; total 227,606,528 B ≈ 227.6 MB) ----
    char* wsb = (char*)d_ws;
    float* F0    = (float*)(wsb);                        // 64 MiB fp32 [B,L,D]
    float* F1    = (float*)(wsb + 67108864);             // 64 MiB fp32 / y16 / ftt partials
    u16*   A16   = (u16*)  (wsb + 134217728);            // 32 MiB bf16 [B,L,D] (x mirror)
    u16*   U16   = (u16*)  (wsb + 167772160);            // 32 MiB bf16 (im2col A2 / qT / new_x)
    u16*   AC16  = (u16*)  (wsb + 201326592);            // 4 MiB  bf16 (W2 at setup / acat)
    float* FTT   = (float*)(wsb + 205520896);            // 8 MiB: WT16 re+im during layers; head partials after
    float* PE    = (float*)(wsb + 213909504);            // 2 MiB  fp32 [1024][512]
    u16*   TRIG  = (u16*)  (wsb + 216006656);            // 256 KiB [128][1024]
    u16*   TCAT  = (u16*)  (wsb + 216268800);            // 256 KiB [1024][128]
    u16*   WQ16  = (u16*)  (wsb + 216530944);            // 1 MiB [2][512][512]
    u16*   WO16  = (u16*)  (wsb + 217579520);            // 1 MiB
    u16*   C1W16 = (u16*)  (wsb + 218628096);            // 4 MiB [2][2048][512]
    u16*   C2W16 = (u16*)  (wsb + 222822400);            // 4 MiB [2][512][2048]
    u16*   FFW16 = (u16*)  (wsb + 227016704);            // 512 KiB
    float* CMEAN = (float*)(wsb + 227540992);            // 64 KiB
    const size_t need_bytes = 227606528;
    if (ws_size < need_bytes) return;   // clean diagnostic failure

    u16* WTRE16 = (u16*)FTT;             // 4 MiB [8][64][4096] bf16 (per-layer)
    u16* WTIM16 = WTRE16 + 2097152;      // 4 MiB

    const int BLD = B_ * L_ * D_;
    dim3 blk(256);

    // tables + weight casts
    k_tables<<<2048, blk, 0, stream>>>(TRIG, TCAT, PE);
    k_cast<<<512,  blk, 0, stream>>>(wq,   WQ16,  524288 / 4);
    k_cast<<<512,  blk, 0, stream>>>(wo,   WO16,  524288 / 4);
    k_cast<<<2048, blk, 0, stream>>>(c1w,  C1W16, 2097152 / 4);
    k_cast<<<2048, blk, 0, stream>>>(c2w,  C2W16, 2097152 / 4);
    k_cast<<<256,  blk, 0, stream>>>(ff_w, FFW16, 262144 / 4);
    // embedding as im2col GEMM: A2 in U16, W2 in AC16, PE added in epilogue
    k_wpad<<<128, blk, 0, stream>>>(conv_w, AC16);
    k_im2col<<<2048, blk, 0, stream>>>(x_enc, U16);
    k_mfma<false, false, false, false, true, true, false, true>
        <<<dim3(4, 256), blk, 0, stream>>>(
        U16, AC16, nullptr, PE, F0, A16, 64, 64, 64, 512, 0, 0);

    float* cur = F0;
    float* alt = F1;
    const dim3 g_big(4, 256);     // M=32768, N=512

    for (int l = 0; l < 2; ++l) {
        const float* bq_l = bq + l * 512;
        const float* bo_l = bo + l * 512;
        const u16* wo16_l = WO16 + (size_t)l * 262144;
        const u16* c1_l   = C1W16 + (size_t)l * DFF_ * D_;
        const u16* c2_l   = C2W16 + (size_t)l * D_ * DFF_;
        const float* fwre_l = fw_re + (size_t)l * H_ * E_ * E_ * M_;
        const float* fwim_l = fw_im + (size_t)l * H_ * E_ * E_ * M_;

        // transpose+cast fourier weights for this layer -> WT16 (coalesced)
        k_wtrans<<<dim3(64, 8, 2), blk, 0, stream>>>(fwre_l, fwim_l, WTRE16, WTIM16);
        // qT[c][b*1024+l] = wq @ x^T + bq  (swapped operands, direct bf16)
        k_mfma<false, true, false, false, false, true><<<dim3(256, 4), blk, 0, stream>>>(
            WQ16 + (size_t)l * 262144, A16, bq_l, nullptr, nullptr, U16,
            512, 512, 512, 32768, 0, 0);
        // forward DFT, transposed output + K-split x4:
        // partials [z=ks*32+b][128 mc][512 c] -> alt (dead until madiff)
        float* ftt4 = alt;
        k_mfma<false, false, false, false, true, false, true>
            <<<dim3(4, 1, 128), blk, 0, stream>>>(
            TRIG, U16, nullptr, nullptr, ftt4, nullptr,
            256, 1024, 32768, 512, 0, 0);
        // complex mode mixing (sums 4 K-slice partials; coalesced reads) -> AC16
        k_modemix<<<512, blk, 0, stream>>>(ftt4, WTRE16, WTIM16, AC16);
        // inverse DFT as GEMM -> U16 = new_x bf16 [B,H,E,L]
        k_mfma<false, false, false, false, false, true><<<dim3(8, 128), blk, 0, stream>>>(
            AC16, TCAT, nullptr, nullptr, nullptr, U16, 128, 128, 128, 1024, 0, 0);
        // x = x + (new_x @ wo^T + bo) -> cur (in-place add)
        k_mfma<true, false, false, true, true, false><<<g_big, blk, 0, stream>>>(
            U16, wo16_l, bo_l, cur, cur, nullptr, 512, 512, 512, 512, 0, 0);
        // x = x - ma(x) -> alt fp32 + A16 bf16 ; swap
        k_madiff<<<dim3(32, 16), blk, 0, stream>>>(cur, alt, A16);
        { float* t = cur; cur = alt; alt = t; }
        // FFN: 2 serial M-chunks of 16384 rows, full DFF per chunk.
        u16* y16 = (u16*)alt;
        for (int c = 0; c < 2; ++c) {
            const size_t aoff = (size_t)c * 16384 * 512;
            k_mfma<false, false, true, false, false, true><<<dim3(16, 128), blk, 0, stream>>>(
                A16 + aoff, c1_l, nullptr, nullptr, nullptr, y16,
                512, 512, 512, 2048, 0, 0);
            k_mfma<false, false, false, true, true, false><<<dim3(4, 128), blk, 0, stream>>>(
                y16, c2_l, nullptr, cur + aoff, cur + aoff, nullptr,
                2048, 2048, 2048, 512, 0, 0);
        }
        // x = xy - ma(xy) -> alt + A16 ; swap
        k_madiff<<<dim3(32, 16), blk, 0, stream>>>(cur, alt, A16);
        { float* t = cur; cur = alt; alt = t; }
    }

    // my_Layernorm: LN then subtract per-(b,d) mean over L
    k_layernorm<<<32768, blk, 0, stream>>>(cur, enc_g, enc_b, alt);
    k_colmean1<<<dim3(B_, 8), 512, 0, stream>>>(alt, FTT);
    k_colmean2<<<64, blk, 0, stream>>>(FTT, CMEAN);
    k_subcol<<<BLD / 256, blk, 0, stream>>>(alt, CMEAN, A16);
    // head Linear -> cur, then fused LN+regression
    k_mfma<true, false, false, false, true, false><<<g_big, blk, 0, stream>>>(
        A16, FFW16, ff_b, nullptr, cur, nullptr, 512, 512, 512, 512, 0, 0);
    k_lnreg<<<32768, blk, 0, stream>>>(cur, ffn_g, ffn_b, reg_w, FTT);
    k_regf2<<<32, blk, 0, stream>>>(FTT, reg_b, out);
}